// Round 2
// baseline (1779.595 us; speedup 1.0000x reference)
//
#include <hip/hip_runtime.h>
#include <hip/hip_bf16.h>

#define N_NODES 10000
#define N_EDGES 160000
#define N_E2    (N_EDGES + N_NODES)   // with self-loops
#define DIM     64
#define HD      256                    // HEADS * DIM
#define N_PRED  2
#define N_CLASS 16
#define N_STEPS 4

typedef __hip_bfloat16 bf16;
__device__ __forceinline__ float b2f(bf16 v) { return __bfloat162float(v); }
__device__ __forceinline__ int clampn(int v) { return v < 0 ? 0 : (v >= N_NODES ? N_NODES - 1 : v); }

struct ConvTable {
    const void* src[17];
    int start[18];   // prefix offsets into xf; start[17] = total
};

// ---------------- dtype detection (1 block) ----------------
// flags[0]: 1 if edge_index is int64 (odd int32 words are all-zero high halves)
// flags[1]: 1 if float arrays are bf16 (even uint16s of x decode to plausible bf16)
__global__ void detect_kernel(const unsigned int* __restrict__ e32,
                              const unsigned short* __restrict__ x16,
                              int* __restrict__ flags) {
    __shared__ int ce, cf;
    if (threadIdx.x == 0) { ce = 0; cf = 0; }
    __syncthreads();
    int le = 0;
    for (int i = threadIdx.x; i < 2048; i += 256)
        le += (e32[2 * i + 1] != 0u) ? 1 : 0;
    int lf = 0;
    for (int i = threadIdx.x; i < 1024; i += 256) {
        unsigned short u = x16[2 * i];
        int ex = (u >> 7) & 0xFF;                 // bf16 exponent field
        lf += (u == 0 || (ex >= 114 && ex <= 141)) ? 1 : 0;  // |v| in [2^-13, 2^14]
    }
    atomicAdd(&ce, le);
    atomicAdd(&cf, lf);
    __syncthreads();
    if (threadIdx.x == 0) {
        flags[0] = (ce < 1024) ? 1 : 0;
        flags[1] = (cf >= 512) ? 1 : 0;
    }
}

// ---------------- normalize all float inputs to fp32 in workspace ----------------
__global__ void convert_kernel(ConvTable tab, const int* __restrict__ flags,
                               float* __restrict__ xf) {
    int i = blockIdx.x * 256 + threadIdx.x;
    if (i >= tab.start[17]) return;
    int j = 0;
    #pragma unroll
    for (int k = 1; k < 17; ++k) j += (i >= tab.start[k]) ? 1 : 0;
    int off = i - tab.start[j];
    float v;
    if (flags[1]) v = b2f(((const bf16*)tab.src[j])[off]);
    else          v = ((const float*)tab.src[j])[off];
    xf[i] = v;
}

// ---------------- CSR by dst ----------------
__global__ void hist_kernel(const int* __restrict__ edges, const int* __restrict__ flags,
                            int* __restrict__ deg) {
    int e = blockIdx.x * 256 + threadIdx.x;
    if (e >= N_E2) return;
    int i64 = flags[0];
    int dst;
    if (e < N_EDGES) dst = clampn(i64 ? edges[2 * (N_EDGES + e)] : edges[N_EDGES + e]);
    else             dst = e - N_EDGES;
    atomicAdd(&deg[dst], 1);
}

__global__ void scan_kernel(const int* __restrict__ deg, int* __restrict__ off) {
    __shared__ int partial[1024];
    const int tid = threadIdx.x;
    const int per = (N_NODES + 1023) / 1024;  // 10
    int local[16];
    int base = tid * per;
    int s = 0;
    for (int i = 0; i < per; ++i) {
        int v = (base + i < N_NODES) ? deg[base + i] : 0;
        local[i] = s;
        s += v;
    }
    partial[tid] = s;
    __syncthreads();
    for (int d = 1; d < 1024; d <<= 1) {
        int t = (tid >= d) ? partial[tid - d] : 0;
        __syncthreads();
        partial[tid] += t;
        __syncthreads();
    }
    int offset = (tid > 0) ? partial[tid - 1] : 0;
    for (int i = 0; i < per; ++i)
        if (base + i < N_NODES) off[base + i] = offset + local[i];
    if (tid == 1023) off[N_NODES] = partial[1023];
}

__global__ void scatter_kernel(const int* __restrict__ edges, const int* __restrict__ flags,
                               const int* __restrict__ off, int* __restrict__ cursor,
                               int* __restrict__ csr_src) {
    int e = blockIdx.x * 256 + threadIdx.x;
    if (e >= N_E2) return;
    int i64 = flags[0];
    int src, dst;
    if (e < N_EDGES) {
        src = clampn(i64 ? edges[2 * e] : edges[e]);
        dst = clampn(i64 ? edges[2 * (N_EDGES + e)] : edges[N_EDGES + e]);
    } else { src = dst = e - N_EDGES; }
    int pos = off[dst] + atomicAdd(&cursor[dst], 1);
    csr_src[pos] = src;
}

// ---------------- encoder: h0 = x @ enc_W + enc_b ----------------
__global__ void encoder_kernel(const float* __restrict__ x, const float* __restrict__ W,
                               const float* __restrict__ b, float* __restrict__ h) {
    __shared__ float xs[4][DIM];
    int g = threadIdx.x >> 6, d = threadIdx.x & 63;
    int n = blockIdx.x * 4 + g;
    xs[g][d] = x[n * DIM + d];
    __syncthreads();
    float acc = b[d];
    #pragma unroll 8
    for (int k = 0; k < DIM; ++k) acc += xs[g][k] * W[k * DIM + d];
    h[n * DIM + d] = acc;
}

// ---------------- xl projection (8 nodes/block to amortize Wl traffic) ----------------
__global__ __launch_bounds__(256) void proj_l_kernel(
        const float* __restrict__ h, const float* __restrict__ Wl,
        const float* __restrict__ bl, float* __restrict__ xl) {
    __shared__ float xs[8][DIM];
    int t = threadIdx.x;
    int n0 = blockIdx.x * 8;
    xs[t >> 6][t & 63]       = h[n0 * DIM + t];
    xs[4 + (t >> 6)][t & 63] = h[(n0 + 4) * DIM + t];
    __syncthreads();
    float a[8] = {0, 0, 0, 0, 0, 0, 0, 0};
    for (int k = 0; k < DIM; ++k) {
        float w = Wl[k * HD + t];
        #pragma unroll
        for (int j = 0; j < 8; ++j) a[j] += xs[j][k] * w;
    }
    float bb = bl[t];
    #pragma unroll
    for (int j = 0; j < 8; ++j) xl[(n0 + j) * HD + t] = a[j] + bb;
}

// ---------------- fused: xr-proj + edge softmax-agg + MLP + ACT (4 nodes/block) ----------------
__global__ __launch_bounds__(256) void fused_node_kernel(
        float* __restrict__ h, const float* __restrict__ xl,
        const float* __restrict__ Wr, const float* __restrict__ br,
        const float* __restrict__ att, const float* __restrict__ gbias,
        const float* __restrict__ W1, const float* __restrict__ b1,
        const float* __restrict__ W2, const float* __restrict__ b2,
        const float* __restrict__ actW, const float* __restrict__ actB,
        const int* __restrict__ off, const int* __restrict__ csr_src,
        float* __restrict__ act_total, float* __restrict__ final_) {
    __shared__ float xs[4][DIM];
    __shared__ float gall[4][HD];
    __shared__ float part4[4][HD];
    __shared__ float u4[4][DIM];
    __shared__ float hn4[4][DIM];
    __shared__ float delta4[4];
    int t = threadIdx.x;
    int n0 = blockIdx.x * 4;
    xs[t >> 6][t & 63] = h[n0 * DIM + t];
    __syncthreads();

    float att_v = att[t];
    float xr_v[4];
    {
        float brv = br[t];
        #pragma unroll
        for (int j = 0; j < 4; ++j) xr_v[j] = brv;
        for (int k = 0; k < DIM; ++k) {
            float w = Wr[k * HD + t];
            #pragma unroll
            for (int j = 0; j < 4; ++j) xr_v[j] += xs[j][k] * w;
        }
    }

    // edge phase: online segment softmax per node (wave = head, lane = channel)
    for (int j = 0; j < 4; ++j) {
        int n = n0 + j;
        int e0 = off[n], e1 = off[n + 1];
        float m = -1e30f, s = 0.f, acc = 0.f;
        float xv = (e0 < e1) ? xl[csr_src[e0] * HD + t] : 0.f;
        for (int e = e0; e < e1; ++e) {
            float xc = xv;
            xv = (e + 1 < e1) ? xl[csr_src[e + 1] * HD + t] : 0.f;  // prefetch next row
            float z = xc + xr_v[j];
            float lr = (z > 0.f) ? z : 0.2f * z;
            float p = lr * att_v;
            #pragma unroll
            for (int mo = 32; mo; mo >>= 1) p += __shfl_xor(p, mo, 64);
            float nm = fmaxf(m, p);
            float sc = __expf(m - nm);
            float w = __expf(p - nm);
            s = s * sc + w;
            acc = acc * sc + w * xc;
            m = nm;
        }
        gall[j][t] = acc / (s + 1e-16f) + gbias[t];
    }
    __syncthreads();

    // MLP layer 1: g[256] -> u[64], 4 nodes share each W1 load
    int d = t & 63, pp = t >> 6;
    {
        float a1[4] = {0, 0, 0, 0};
        for (int k = pp * 64; k < pp * 64 + 64; ++k) {
            float w = W1[k * DIM + d];
            #pragma unroll
            for (int j = 0; j < 4; ++j) a1[j] += gall[j][k] * w;
        }
        #pragma unroll
        for (int j = 0; j < 4; ++j) part4[j][t] = a1[j];
    }
    __syncthreads();
    if (t < DIM) {
        float bb = b1[t];
        #pragma unroll
        for (int j = 0; j < 4; ++j) {
            float v = part4[j][t] + part4[j][64 + t] + part4[j][128 + t] + part4[j][192 + t] + bb;
            u4[j][t] = fmaxf(v, 0.f);
        }
    }
    __syncthreads();
    // MLP layer 2: u[64] -> hn[64]
    {
        float a2[4] = {0, 0, 0, 0};
        for (int k = pp * 16; k < pp * 16 + 16; ++k) {
            float w = W2[k * DIM + d];
            #pragma unroll
            for (int j = 0; j < 4; ++j) a2[j] += u4[j][k] * w;
        }
        #pragma unroll
        for (int j = 0; j < 4; ++j) part4[j][t] = a2[j];
    }
    __syncthreads();
    if (t < DIM) {
        float bb = b2[t];
        #pragma unroll
        for (int j = 0; j < 4; ++j)
            hn4[j][t] = part4[j][t] + part4[j][64 + t] + part4[j][128 + t] + part4[j][192 + t] + bb;
    }
    __syncthreads();

    // ACT halting: wave j handles node j
    {
        float p = hn4[pp][d] * actW[d];
        #pragma unroll
        for (int mo = 32; mo; mo >>= 1) p += __shfl_xor(p, mo, 64);
        if (d == 0) {
            float term = 1.f / (1.f + __expf(-(p + actB[0])));
            float tot = act_total[n0 + pp];
            float nt = fminf(tot + term, 1.f);
            float dl = fminf(term, nt - tot);
            act_total[n0 + pp] = tot + dl;
            delta4[pp] = dl;
        }
    }
    __syncthreads();
    {
        float hv = hn4[pp][d];
        final_[(n0 + pp) * DIM + d] += delta4[pp] * hv;
        h[(n0 + pp) * DIM + d] = hv;
    }
}

// ---------------- decoder + log_softmax ----------------
__global__ void decoder_kernel(const float* __restrict__ final_,
                               const float* __restrict__ decW, const float* __restrict__ decB,
                               const int* __restrict__ flags, void* __restrict__ outv) {
    int id = blockIdx.x * 256 + threadIdx.x;
    if (id >= N_NODES * N_PRED * N_CLASS) return;
    int n = id >> 5, r = id & 31, p = r >> 4, c = r & 15;
    float acc = decB[p * N_CLASS + c];
    for (int dd = 0; dd < DIM; ++dd)
        acc += final_[n * DIM + dd] * decW[(p * DIM + dd) * N_CLASS + c];
    float mx = acc;
    #pragma unroll
    for (int mo = 8; mo; mo >>= 1) mx = fmaxf(mx, __shfl_xor(mx, mo, 64));
    float ex = __expf(acc - mx);
    float ss = ex;
    #pragma unroll
    for (int mo = 8; mo; mo >>= 1) ss += __shfl_xor(ss, mo, 64);
    float ov = acc - mx - logf(ss);
    int oi = p * (N_NODES * N_CLASS) + n * N_CLASS + c;
    if (flags[1]) ((bf16*)outv)[oi] = __float2bfloat16(ov);
    else          ((float*)outv)[oi] = ov;
}

// ---------------- host launcher ----------------
static size_t align256(size_t x) { return (x + 255) & ~size_t(255); }

extern "C" void kernel_launch(void* const* d_in, const int* in_sizes, int n_in,
                              void* d_out, int out_size, void* d_ws, size_t ws_size,
                              hipStream_t stream) {
    const int* edges = (const int*)d_in[1];

    // float-input table (dict order, skipping edge_index and num_steps)
    static const int fids[17] = {0, 2, 3, 4, 5, 6, 7, 8, 9, 10, 11, 12, 13, 14, 15, 16, 17};
    ConvTable tab;
    int cum = 0;
    for (int i = 0; i < 17; ++i) {
        tab.src[i] = d_in[fids[i]];
        tab.start[i] = cum;
        cum += in_sizes[fids[i]];
    }
    tab.start[17] = cum;

    // workspace carve-up (~19 MB)
    char* w = (char*)d_ws;
    size_t o = 0;
    int* flags     = (int*)(w + o); o = align256(o + 16 * sizeof(int));
    int* off       = (int*)(w + o); o = align256(o + (N_NODES + 1) * sizeof(int));
    int* deg       = (int*)(w + o); o = align256(o + N_NODES * sizeof(int));
    int* cursor    = (int*)(w + o); o = align256(o + N_NODES * sizeof(int));
    int* csr_src   = (int*)(w + o); o = align256(o + N_E2 * sizeof(int));
    float* xf      = (float*)(w + o); o = align256(o + (size_t)cum * sizeof(float));
    float* h       = (float*)(w + o); o = align256(o + (size_t)N_NODES * DIM * sizeof(float));
    float* xl      = (float*)(w + o); o = align256(o + (size_t)N_NODES * HD * sizeof(float));
    float* act_tot = (float*)(w + o); o = align256(o + N_NODES * sizeof(float));
    float* final_  = (float*)(w + o); o = align256(o + (size_t)N_NODES * DIM * sizeof(float));
    if (o > ws_size) return;  // diagnostic: zero output => ws too small

    // named fp32 views into xf
    const float* Xf   = xf + tab.start[0];
    const float* encW = xf + tab.start[1];
    const float* encB = xf + tab.start[2];
    const float* Wl   = xf + tab.start[3];
    const float* bl   = xf + tab.start[4];
    const float* Wr   = xf + tab.start[5];
    const float* br   = xf + tab.start[6];
    const float* att  = xf + tab.start[7];
    const float* gbias= xf + tab.start[8];
    const float* W1   = xf + tab.start[9];
    const float* b1   = xf + tab.start[10];
    const float* W2   = xf + tab.start[11];
    const float* b2   = xf + tab.start[12];
    const float* actW = xf + tab.start[13];
    const float* actB = xf + tab.start[14];
    const float* decW = xf + tab.start[15];
    const float* decB = xf + tab.start[16];

    hipMemsetAsync(deg,     0, N_NODES * sizeof(int), stream);
    hipMemsetAsync(cursor,  0, N_NODES * sizeof(int), stream);
    hipMemsetAsync(act_tot, 0, N_NODES * sizeof(float), stream);
    hipMemsetAsync(final_,  0, (size_t)N_NODES * DIM * sizeof(float), stream);

    detect_kernel<<<1, 256, 0, stream>>>((const unsigned int*)d_in[1],
                                         (const unsigned short*)d_in[0], flags);
    convert_kernel<<<(cum + 255) / 256, 256, 0, stream>>>(tab, flags, xf);

    int eb = (N_E2 + 255) / 256;
    hist_kernel<<<eb, 256, 0, stream>>>(edges, flags, deg);
    scan_kernel<<<1, 1024, 0, stream>>>(deg, off);
    scatter_kernel<<<eb, 256, 0, stream>>>(edges, flags, off, cursor, csr_src);

    encoder_kernel<<<N_NODES / 4, 256, 0, stream>>>(Xf, encW, encB, h);

    for (int step = 0; step < N_STEPS; ++step) {
        proj_l_kernel<<<N_NODES / 8, 256, 0, stream>>>(h, Wl, bl, xl);
        fused_node_kernel<<<N_NODES / 4, 256, 0, stream>>>(
            h, xl, Wr, br, att, gbias, W1, b1, W2, b2, actW, actB,
            off, csr_src, act_tot, final_);
    }

    int db = (N_NODES * N_PRED * N_CLASS + 255) / 256;
    decoder_kernel<<<db, 256, 0, stream>>>(final_, decW, decB, flags, d_out);
}

// Round 3
// 758.166 us; speedup vs baseline: 2.3472x; 2.3472x over previous
//
#include <hip/hip_runtime.h>
#include <hip/hip_bf16.h>

#define N_NODES 10000
#define N_EDGES 160000
#define N_E2    (N_EDGES + N_NODES)   // with self-loops
#define DIM     64
#define HD      256                    // HEADS * DIM
#define N_PRED  2
#define N_CLASS 16
#define N_STEPS 4

typedef __hip_bfloat16 bf16;
__device__ __forceinline__ float b2f(bf16 v) { return __bfloat162float(v); }
__device__ __forceinline__ int clampn(int v) { return v < 0 ? 0 : (v >= N_NODES ? N_NODES - 1 : v); }

struct ConvTable {
    const void* src[17];
    int start[18];   // prefix offsets into xf; start[17] = total
};

// ---------------- dtype detection (1 block) ----------------
__global__ void detect_kernel(const unsigned int* __restrict__ e32,
                              const unsigned short* __restrict__ x16,
                              int* __restrict__ flags) {
    __shared__ int ce, cf;
    if (threadIdx.x == 0) { ce = 0; cf = 0; }
    __syncthreads();
    int le = 0;
    for (int i = threadIdx.x; i < 2048; i += 256)
        le += (e32[2 * i + 1] != 0u) ? 1 : 0;
    int lf = 0;
    for (int i = threadIdx.x; i < 1024; i += 256) {
        unsigned short u = x16[2 * i];
        int ex = (u >> 7) & 0xFF;
        lf += (u == 0 || (ex >= 114 && ex <= 141)) ? 1 : 0;
    }
    atomicAdd(&ce, le);
    atomicAdd(&cf, lf);
    __syncthreads();
    if (threadIdx.x == 0) {
        flags[0] = (ce < 1024) ? 1 : 0;   // edge_index is int64
        flags[1] = (cf >= 512) ? 1 : 0;   // floats are bf16
    }
}

// ---------------- normalize all float inputs to fp32 in workspace ----------------
__global__ void convert_kernel(ConvTable tab, const int* __restrict__ flags,
                               float* __restrict__ xf) {
    int i = blockIdx.x * 256 + threadIdx.x;
    if (i >= tab.start[17]) return;
    int j = 0;
    #pragma unroll
    for (int k = 1; k < 17; ++k) j += (i >= tab.start[k]) ? 1 : 0;
    int off = i - tab.start[j];
    float v;
    if (flags[1]) v = b2f(((const bf16*)tab.src[j])[off]);
    else          v = ((const float*)tab.src[j])[off];
    xf[i] = v;
}

// ---------------- CSR by dst ----------------
__global__ void hist_kernel(const int* __restrict__ edges, const int* __restrict__ flags,
                            int* __restrict__ deg) {
    int e = blockIdx.x * 256 + threadIdx.x;
    if (e >= N_E2) return;
    int i64 = flags[0];
    int dst;
    if (e < N_EDGES) dst = clampn(i64 ? edges[2 * (N_EDGES + e)] : edges[N_EDGES + e]);
    else             dst = e - N_EDGES;
    atomicAdd(&deg[dst], 1);
}

__global__ void scan_kernel(const int* __restrict__ deg, int* __restrict__ off) {
    __shared__ int partial[1024];
    const int tid = threadIdx.x;
    const int per = (N_NODES + 1023) / 1024;  // 10
    int local[16];
    int base = tid * per;
    int s = 0;
    for (int i = 0; i < per; ++i) {
        int v = (base + i < N_NODES) ? deg[base + i] : 0;
        local[i] = s;
        s += v;
    }
    partial[tid] = s;
    __syncthreads();
    for (int d = 1; d < 1024; d <<= 1) {
        int t = (tid >= d) ? partial[tid - d] : 0;
        __syncthreads();
        partial[tid] += t;
        __syncthreads();
    }
    int offset = (tid > 0) ? partial[tid - 1] : 0;
    for (int i = 0; i < per; ++i)
        if (base + i < N_NODES) off[base + i] = offset + local[i];
    if (tid == 1023) off[N_NODES] = partial[1023];
}

__global__ void scatter_kernel(const int* __restrict__ edges, const int* __restrict__ flags,
                               const int* __restrict__ off, int* __restrict__ cursor,
                               int* __restrict__ csr_src, int* __restrict__ csr_dst) {
    int e = blockIdx.x * 256 + threadIdx.x;
    if (e >= N_E2) return;
    int i64 = flags[0];
    int src, dst;
    if (e < N_EDGES) {
        src = clampn(i64 ? edges[2 * e] : edges[e]);
        dst = clampn(i64 ? edges[2 * (N_EDGES + e)] : edges[N_EDGES + e]);
    } else { src = dst = e - N_EDGES; }
    int pos = off[dst] + atomicAdd(&cursor[dst], 1);
    csr_src[pos] = src;
    csr_dst[pos] = dst;
}

// ---------------- encoder: h0 = x @ enc_W + enc_b ----------------
__global__ void encoder_kernel(const float* __restrict__ x, const float* __restrict__ W,
                               const float* __restrict__ b, float* __restrict__ h) {
    __shared__ float xs[4][DIM];
    int g = threadIdx.x >> 6, d = threadIdx.x & 63;
    int n = blockIdx.x * 4 + g;
    xs[g][d] = x[n * DIM + d];
    __syncthreads();
    float acc = b[d];
    #pragma unroll 8
    for (int k = 0; k < DIM; ++k) acc += xs[g][k] * W[k * DIM + d];
    h[n * DIM + d] = acc;
}

// ---------------- projections: xl AND xr (8 nodes/block) ----------------
__global__ __launch_bounds__(256) void proj_kernel(
        const float* __restrict__ h,
        const float* __restrict__ Wl, const float* __restrict__ bl,
        const float* __restrict__ Wr, const float* __restrict__ br,
        float* __restrict__ xl, float* __restrict__ xr) {
    __shared__ float xs[8][DIM];
    int t = threadIdx.x;
    int n0 = blockIdx.x * 8;
    xs[t >> 6][t & 63]       = h[n0 * DIM + t];
    xs[4 + (t >> 6)][t & 63] = h[(n0 + 4) * DIM + t];
    __syncthreads();
    float al[8] = {0,0,0,0,0,0,0,0};
    float ar[8] = {0,0,0,0,0,0,0,0};
    for (int k = 0; k < DIM; ++k) {
        float wl = Wl[k * HD + t];
        float wr = Wr[k * HD + t];
        #pragma unroll
        for (int j = 0; j < 8; ++j) { al[j] += xs[j][k] * wl; ar[j] += xs[j][k] * wr; }
    }
    float bbl = bl[t], bbr = br[t];
    #pragma unroll
    for (int j = 0; j < 8; ++j) {
        xl[(n0 + j) * HD + t] = al[j] + bbl;
        xr[(n0 + j) * HD + t] = ar[j] + bbr;
    }
}

// ---------------- edge-parallel logits: wave per edge ----------------
// logits[e][h] = sum_c leakyrelu(xl[src][h][c]+xr[dst][h][c]) * att[h][c]
__global__ __launch_bounds__(256) void edge_logit_kernel(
        const float* __restrict__ xl, const float* __restrict__ xr,
        const float* __restrict__ att,
        const int* __restrict__ csr_src, const int* __restrict__ csr_dst,
        float* __restrict__ logits) {
    int gid = blockIdx.x * 4 + (threadIdx.x >> 6);
    if (gid >= N_E2) return;
    int l = threadIdx.x & 63;
    int s = csr_src[gid], d = csr_dst[gid];
    float4 a = ((const float4*)(xl + (size_t)s * HD))[l];
    float4 b = ((const float4*)(xr + (size_t)d * HD))[l];
    float4 av = ((const float4*)att)[l];
    float z0 = a.x + b.x, z1 = a.y + b.y, z2 = a.z + b.z, z3 = a.w + b.w;
    z0 = (z0 > 0.f) ? z0 : 0.2f * z0;
    z1 = (z1 > 0.f) ? z1 : 0.2f * z1;
    z2 = (z2 > 0.f) ? z2 : 0.2f * z2;
    z3 = (z3 > 0.f) ? z3 : 0.2f * z3;
    float p = z0 * av.x + z1 * av.y + z2 * av.z + z3 * av.w;
    // reduce within each 16-lane head group
    #pragma unroll
    for (int mo = 8; mo; mo >>= 1) p += __shfl_xor(p, mo, 64);
    if ((l & 15) == 0) logits[gid * 4 + (l >> 4)] = p;
}

// ---------------- node kernel: segment softmax + aggregation + MLP + ACT ----------------
// block = 1 node; wave w = head w; lane = channel within head
__global__ __launch_bounds__(256) void node_kernel(
        float* __restrict__ h, const float* __restrict__ xl,
        const float* __restrict__ logits, const float* __restrict__ gbias,
        const float* __restrict__ W1, const float* __restrict__ b1,
        const float* __restrict__ W2, const float* __restrict__ b2,
        const float* __restrict__ actW, const float* __restrict__ actB,
        const int* __restrict__ off, const int* __restrict__ csr_src,
        float* __restrict__ act_total, float* __restrict__ final_) {
    __shared__ float gs[HD];
    __shared__ float part[256];
    __shared__ float us[DIM];
    __shared__ float hns[DIM];
    __shared__ float delta_s;
    int n = blockIdx.x;
    int t = threadIdx.x, w = t >> 6, l = t & 63;
    int e0 = off[n], e1 = off[n + 1];

    // per-head segment max / sum (strided over lanes; deg>=1 guaranteed by self-loop)
    float lm = -1e30f;
    for (int p = e0 + l; p < e1; p += 64) lm = fmaxf(lm, logits[p * 4 + w]);
    #pragma unroll
    for (int mo = 32; mo; mo >>= 1) lm = fmaxf(lm, __shfl_xor(lm, mo, 64));
    float ls = 0.f;
    for (int p = e0 + l; p < e1; p += 64) ls += __expf(logits[p * 4 + w] - lm);
    #pragma unroll
    for (int mo = 32; mo; mo >>= 1) ls += __shfl_xor(ls, mo, 64);
    float inv_s = 1.f / (ls + 1e-16f);

    // aggregation: acc[t] = sum_e exp(logit-lm) * xl[src_e][t]  (1-FMA dep chain)
    float acc = 0.f;
    float xv = xl[(size_t)csr_src[e0] * HD + t];
    float lg = logits[e0 * 4 + w];
    for (int e = e0; e < e1; ++e) {
        float xc = xv, lc = lg;
        if (e + 1 < e1) {
            int sn = csr_src[e + 1];
            xv = xl[(size_t)sn * HD + t];
            lg = logits[(e + 1) * 4 + w];
        }
        acc += __expf(lc - lm) * xc;
    }
    gs[t] = acc * inv_s + gbias[t];
    __syncthreads();

    // MLP layer 1: g[256] -> u[64]
    float a1 = 0.f;
    for (int k = w * 64; k < w * 64 + 64; ++k) a1 += gs[k] * W1[k * DIM + l];
    part[t] = a1;
    __syncthreads();
    if (t < DIM)
        us[t] = fmaxf(part[t] + part[64 + t] + part[128 + t] + part[192 + t] + b1[t], 0.f);
    __syncthreads();

    // MLP layer 2: u[64] -> hn[64]
    float a2 = 0.f;
    for (int k = w * 16; k < w * 16 + 16; ++k) a2 += us[k] * W2[k * DIM + l];
    part[t] = a2;
    __syncthreads();
    if (t < DIM)
        hns[t] = part[t] + part[64 + t] + part[128 + t] + part[192 + t] + b2[t];
    __syncthreads();

    // ACT halting (wave 0)
    if (w == 0) {
        float p = hns[l] * actW[l];
        #pragma unroll
        for (int mo = 32; mo; mo >>= 1) p += __shfl_xor(p, mo, 64);
        if (l == 0) {
            float term = 1.f / (1.f + __expf(-(p + actB[0])));
            float tot = act_total[n];
            float nt = fminf(tot + term, 1.f);
            float dl = fminf(term, nt - tot);
            act_total[n] = tot + dl;
            delta_s = dl;
        }
    }
    __syncthreads();
    if (t < DIM) {
        float hv = hns[t];
        final_[n * DIM + t] += delta_s * hv;
        h[n * DIM + t] = hv;
    }
}

// ---------------- decoder + log_softmax ----------------
__global__ void decoder_kernel(const float* __restrict__ final_,
                               const float* __restrict__ decW, const float* __restrict__ decB,
                               const int* __restrict__ flags, void* __restrict__ outv) {
    int id = blockIdx.x * 256 + threadIdx.x;
    if (id >= N_NODES * N_PRED * N_CLASS) return;
    int n = id >> 5, r = id & 31, p = r >> 4, c = r & 15;
    float acc = decB[p * N_CLASS + c];
    for (int dd = 0; dd < DIM; ++dd)
        acc += final_[n * DIM + dd] * decW[(p * DIM + dd) * N_CLASS + c];
    float mx = acc;
    #pragma unroll
    for (int mo = 8; mo; mo >>= 1) mx = fmaxf(mx, __shfl_xor(mx, mo, 64));
    float ex = __expf(acc - mx);
    float ss = ex;
    #pragma unroll
    for (int mo = 8; mo; mo >>= 1) ss += __shfl_xor(ss, mo, 64);
    float ov = acc - mx - logf(ss);
    int oi = p * (N_NODES * N_CLASS) + n * N_CLASS + c;
    if (flags[1]) ((bf16*)outv)[oi] = __float2bfloat16(ov);
    else          ((float*)outv)[oi] = ov;
}

// ---------------- host launcher ----------------
static size_t align256(size_t x) { return (x + 255) & ~size_t(255); }

extern "C" void kernel_launch(void* const* d_in, const int* in_sizes, int n_in,
                              void* d_out, int out_size, void* d_ws, size_t ws_size,
                              hipStream_t stream) {
    const int* edges = (const int*)d_in[1];

    static const int fids[17] = {0, 2, 3, 4, 5, 6, 7, 8, 9, 10, 11, 12, 13, 14, 15, 16, 17};
    ConvTable tab;
    int cum = 0;
    for (int i = 0; i < 17; ++i) {
        tab.src[i] = d_in[fids[i]];
        tab.start[i] = cum;
        cum += in_sizes[fids[i]];
    }
    tab.start[17] = cum;

    // workspace carve-up (~33 MB)
    char* w = (char*)d_ws;
    size_t o = 0;
    int* flags     = (int*)(w + o); o = align256(o + 16 * sizeof(int));
    int* off       = (int*)(w + o); o = align256(o + (N_NODES + 1) * sizeof(int));
    int* deg       = (int*)(w + o); o = align256(o + N_NODES * sizeof(int));
    int* cursor    = (int*)(w + o); o = align256(o + N_NODES * sizeof(int));
    int* csr_src   = (int*)(w + o); o = align256(o + N_E2 * sizeof(int));
    int* csr_dst   = (int*)(w + o); o = align256(o + N_E2 * sizeof(int));
    float* logits  = (float*)(w + o); o = align256(o + (size_t)N_E2 * 4 * sizeof(float));
    float* xf      = (float*)(w + o); o = align256(o + (size_t)cum * sizeof(float));
    float* h       = (float*)(w + o); o = align256(o + (size_t)N_NODES * DIM * sizeof(float));
    float* xl      = (float*)(w + o); o = align256(o + (size_t)N_NODES * HD * sizeof(float));
    float* xr      = (float*)(w + o); o = align256(o + (size_t)N_NODES * HD * sizeof(float));
    float* act_tot = (float*)(w + o); o = align256(o + N_NODES * sizeof(float));
    float* final_  = (float*)(w + o); o = align256(o + (size_t)N_NODES * DIM * sizeof(float));
    if (o > ws_size) return;  // diagnostic: zero output => ws too small

    const float* Xf   = xf + tab.start[0];
    const float* encW = xf + tab.start[1];
    const float* encB = xf + tab.start[2];
    const float* Wl   = xf + tab.start[3];
    const float* bl   = xf + tab.start[4];
    const float* Wr   = xf + tab.start[5];
    const float* br   = xf + tab.start[6];
    const float* att  = xf + tab.start[7];
    const float* gbias= xf + tab.start[8];
    const float* W1   = xf + tab.start[9];
    const float* b1   = xf + tab.start[10];
    const float* W2   = xf + tab.start[11];
    const float* b2   = xf + tab.start[12];
    const float* actW = xf + tab.start[13];
    const float* actB = xf + tab.start[14];
    const float* decW = xf + tab.start[15];
    const float* decB = xf + tab.start[16];

    hipMemsetAsync(deg,     0, N_NODES * sizeof(int), stream);
    hipMemsetAsync(cursor,  0, N_NODES * sizeof(int), stream);
    hipMemsetAsync(act_tot, 0, N_NODES * sizeof(float), stream);
    hipMemsetAsync(final_,  0, (size_t)N_NODES * DIM * sizeof(float), stream);

    detect_kernel<<<1, 256, 0, stream>>>((const unsigned int*)d_in[1],
                                         (const unsigned short*)d_in[0], flags);
    convert_kernel<<<(cum + 255) / 256, 256, 0, stream>>>(tab, flags, xf);

    int eb = (N_E2 + 255) / 256;
    hist_kernel<<<eb, 256, 0, stream>>>(edges, flags, deg);
    scan_kernel<<<1, 1024, 0, stream>>>(deg, off);
    scatter_kernel<<<eb, 256, 0, stream>>>(edges, flags, off, cursor, csr_src, csr_dst);

    encoder_kernel<<<N_NODES / 4, 256, 0, stream>>>(Xf, encW, encB, h);

    int lb = (N_E2 + 3) / 4;
    for (int step = 0; step < N_STEPS; ++step) {
        proj_kernel<<<N_NODES / 8, 256, 0, stream>>>(h, Wl, bl, Wr, br, xl, xr);
        edge_logit_kernel<<<lb, 256, 0, stream>>>(xl, xr, att, csr_src, csr_dst, logits);
        node_kernel<<<N_NODES, 256, 0, stream>>>(h, xl, logits, gbias, W1, b1, W2, b2,
                                                 actW, actB, off, csr_src, act_tot, final_);
    }

    int db = (N_NODES * N_PRED * N_CLASS + 255) / 256;
    decoder_kernel<<<db, 256, 0, stream>>>(final_, decW, decB, flags, d_out);
}

// Round 4
// 494.062 us; speedup vs baseline: 3.6020x; 1.5346x over previous
//
#include <hip/hip_runtime.h>
#include <hip/hip_bf16.h>

#define N_NODES 10000
#define N_EDGES 160000
#define N_E2    (N_EDGES + N_NODES)   // with self-loops
#define DIM     64
#define HD      256                    // HEADS * DIM
#define N_PRED  2
#define N_CLASS 16
#define N_STEPS 4

typedef __hip_bfloat16 bf16;
__device__ __forceinline__ float b2f(bf16 v) { return __bfloat162float(v); }
__device__ __forceinline__ int clampn(int v) { return v < 0 ? 0 : (v >= N_NODES ? N_NODES - 1 : v); }

struct ConvTable {
    const void* src[17];
    int start[18];   // prefix offsets into xf; start[17] = total
};

// ---------------- dtype detection (1 block) ----------------
__global__ void detect_kernel(const unsigned int* __restrict__ e32,
                              const unsigned short* __restrict__ x16,
                              int* __restrict__ flags) {
    __shared__ int ce, cf;
    if (threadIdx.x == 0) { ce = 0; cf = 0; }
    __syncthreads();
    int le = 0;
    for (int i = threadIdx.x; i < 2048; i += 256)
        le += (e32[2 * i + 1] != 0u) ? 1 : 0;
    int lf = 0;
    for (int i = threadIdx.x; i < 1024; i += 256) {
        unsigned short u = x16[2 * i];
        int ex = (u >> 7) & 0xFF;
        lf += (u == 0 || (ex >= 114 && ex <= 141)) ? 1 : 0;
    }
    atomicAdd(&ce, le);
    atomicAdd(&cf, lf);
    __syncthreads();
    if (threadIdx.x == 0) {
        flags[0] = (ce < 1024) ? 1 : 0;   // edge_index is int64
        flags[1] = (cf >= 512) ? 1 : 0;   // floats are bf16
    }
}

// ---------------- normalize all float inputs to fp32 in workspace ----------------
__global__ void convert_kernel(ConvTable tab, const int* __restrict__ flags,
                               float* __restrict__ xf) {
    int i = blockIdx.x * 256 + threadIdx.x;
    if (i >= tab.start[17]) return;
    int j = 0;
    #pragma unroll
    for (int k = 1; k < 17; ++k) j += (i >= tab.start[k]) ? 1 : 0;
    int off = i - tab.start[j];
    float v;
    if (flags[1]) v = b2f(((const bf16*)tab.src[j])[off]);
    else          v = ((const float*)tab.src[j])[off];
    xf[i] = v;
}

// ---------------- CSR by dst ----------------
__global__ void hist_kernel(const int* __restrict__ edges, const int* __restrict__ flags,
                            int* __restrict__ deg) {
    int e = blockIdx.x * 256 + threadIdx.x;
    if (e >= N_E2) return;
    int i64 = flags[0];
    int dst;
    if (e < N_EDGES) dst = clampn(i64 ? edges[2 * (N_EDGES + e)] : edges[N_EDGES + e]);
    else             dst = e - N_EDGES;
    atomicAdd(&deg[dst], 1);
}

__global__ void scan_kernel(const int* __restrict__ deg, int* __restrict__ off) {
    __shared__ int partial[1024];
    const int tid = threadIdx.x;
    const int per = (N_NODES + 1023) / 1024;  // 10
    int local[16];
    int base = tid * per;
    int s = 0;
    for (int i = 0; i < per; ++i) {
        int v = (base + i < N_NODES) ? deg[base + i] : 0;
        local[i] = s;
        s += v;
    }
    partial[tid] = s;
    __syncthreads();
    for (int d = 1; d < 1024; d <<= 1) {
        int t = (tid >= d) ? partial[tid - d] : 0;
        __syncthreads();
        partial[tid] += t;
        __syncthreads();
    }
    int offset = (tid > 0) ? partial[tid - 1] : 0;
    for (int i = 0; i < per; ++i)
        if (base + i < N_NODES) off[base + i] = offset + local[i];
    if (tid == 1023) off[N_NODES] = partial[1023];
}

__global__ void scatter_kernel(const int* __restrict__ edges, const int* __restrict__ flags,
                               const int* __restrict__ off, int* __restrict__ cursor,
                               int* __restrict__ csr_src) {
    int e = blockIdx.x * 256 + threadIdx.x;
    if (e >= N_E2) return;
    int i64 = flags[0];
    int src, dst;
    if (e < N_EDGES) {
        src = clampn(i64 ? edges[2 * e] : edges[e]);
        dst = clampn(i64 ? edges[2 * (N_EDGES + e)] : edges[N_EDGES + e]);
    } else { src = dst = e - N_EDGES; }
    int pos = off[dst] + atomicAdd(&cursor[dst], 1);
    csr_src[pos] = src;
}

// ---------------- encoder: h0 = x @ enc_W + enc_b ----------------
__global__ void encoder_kernel(const float* __restrict__ x, const float* __restrict__ W,
                               const float* __restrict__ b, float* __restrict__ h) {
    __shared__ float xs[4][DIM];
    int g = threadIdx.x >> 6, d = threadIdx.x & 63;
    int n = blockIdx.x * 4 + g;
    xs[g][d] = x[n * DIM + d];
    __syncthreads();
    float acc = b[d];
    #pragma unroll 8
    for (int k = 0; k < DIM; ++k) acc += xs[g][k] * W[k * DIM + d];
    h[n * DIM + d] = acc;
}

// ---------------- projections: xl AND xr (8 nodes/block) ----------------
__global__ __launch_bounds__(256) void proj_kernel(
        const float* __restrict__ h,
        const float* __restrict__ Wl, const float* __restrict__ bl,
        const float* __restrict__ Wr, const float* __restrict__ br,
        float* __restrict__ xl, float* __restrict__ xr) {
    __shared__ float xs[8][DIM];
    int t = threadIdx.x;
    int n0 = blockIdx.x * 8;
    xs[t >> 6][t & 63]       = h[n0 * DIM + t];
    xs[4 + (t >> 6)][t & 63] = h[(n0 + 4) * DIM + t];
    __syncthreads();
    float al[8] = {0,0,0,0,0,0,0,0};
    float ar[8] = {0,0,0,0,0,0,0,0};
    for (int k = 0; k < DIM; ++k) {
        float wl = Wl[k * HD + t];
        float wr = Wr[k * HD + t];
        #pragma unroll
        for (int j = 0; j < 8; ++j) { al[j] += xs[j][k] * wl; ar[j] += xs[j][k] * wr; }
    }
    float bbl = bl[t], bbr = br[t];
    #pragma unroll
    for (int j = 0; j < 8; ++j) {
        xl[(n0 + j) * HD + t] = al[j] + bbl;
        xr[(n0 + j) * HD + t] = ar[j] + bbr;
    }
}

// ---------------- fused node kernel: logits + flash softmax-agg + MLP + ACT ----------
// block = 1 node; 4 waves walk interleaved edge subsets with private online-softmax
// state; one xl-row gather serves both logit and aggregation. Flash-merge at end.
__global__ __launch_bounds__(256) void node_fused_kernel(
        float* __restrict__ h, const float* __restrict__ xl, const float* __restrict__ xr,
        const float* __restrict__ att, const float* __restrict__ gbias,
        const float* __restrict__ W1, const float* __restrict__ b1,
        const float* __restrict__ W2, const float* __restrict__ b2,
        const float* __restrict__ actW, const float* __restrict__ actB,
        const int* __restrict__ off, const int* __restrict__ csr_src,
        float* __restrict__ act_total, float* __restrict__ final_) {
    __shared__ float red_m[4][4];     // [wave][head]
    __shared__ float red_s[4][4];
    __shared__ float red_acc[4][HD];  // [wave][channel]  4 KB
    __shared__ float gs[HD];
    __shared__ float part[256];
    __shared__ float us[DIM];
    __shared__ float hns[DIM];
    __shared__ float delta_s;
    int n = blockIdx.x;
    int t = threadIdx.x, w = t >> 6, l = t & 63;
    int e0 = off[n], e1 = off[n + 1];

    // block-uniform per-node data: lane l holds channels [4l, 4l+4)
    const float4 xr4 = ((const float4*)(xr + (size_t)n * HD))[l];
    const float4 at4 = ((const float4*)att)[l];

    // edge phase: wave w handles edges e0+w, e0+w+4, ... with online softmax
    float m = -1e30f, s = 0.f;
    float4 acc = {0.f, 0.f, 0.f, 0.f};
    int e = e0 + w;
    int sp = (e < e1) ? csr_src[e] : 0;
    float4 r = (e < e1) ? ((const float4*)(xl + (size_t)sp * HD))[l]
                        : (float4){0.f, 0.f, 0.f, 0.f};
    for (; e < e1; e += 4) {
        float4 cur = r;
        int en = e + 4;
        if (en < e1) {                     // 1-deep prefetch of next row
            int sn = csr_src[en];
            r = ((const float4*)(xl + (size_t)sn * HD))[l];
        }
        float z0 = cur.x + xr4.x, z1 = cur.y + xr4.y, z2 = cur.z + xr4.z, z3 = cur.w + xr4.w;
        z0 = (z0 > 0.f) ? z0 : 0.2f * z0;
        z1 = (z1 > 0.f) ? z1 : 0.2f * z1;
        z2 = (z2 > 0.f) ? z2 : 0.2f * z2;
        z3 = (z3 > 0.f) ? z3 : 0.2f * z3;
        float p = z0 * at4.x + z1 * at4.y + z2 * at4.z + z3 * at4.w;
        #pragma unroll
        for (int mo = 8; mo; mo >>= 1) p += __shfl_xor(p, mo, 64);  // 16-lane head reduce
        float nm = fmaxf(m, p);
        float sc = __expf(m - nm);
        float wv = __expf(p - nm);
        s = s * sc + wv;
        acc.x = acc.x * sc + wv * cur.x;
        acc.y = acc.y * sc + wv * cur.y;
        acc.z = acc.z * sc + wv * cur.z;
        acc.w = acc.w * sc + wv * cur.w;
        m = nm;
    }
    // publish per-wave state
    if ((l & 15) == 0) { red_m[w][l >> 4] = m; red_s[w][l >> 4] = s; }
    ((float4*)red_acc[w])[l] = acc;
    __syncthreads();

    // flash-merge the 4 wave-partials: thread t = channel c
    {
        int c = t, hh = c >> 6;
        float m0 = red_m[0][hh], m1 = red_m[1][hh], m2 = red_m[2][hh], m3 = red_m[3][hh];
        float mm = fmaxf(fmaxf(m0, m1), fmaxf(m2, m3));
        float f0 = __expf(m0 - mm), f1 = __expf(m1 - mm),
              f2 = __expf(m2 - mm), f3 = __expf(m3 - mm);
        float ss = red_s[0][hh] * f0 + red_s[1][hh] * f1 + red_s[2][hh] * f2 + red_s[3][hh] * f3;
        float aa = red_acc[0][c] * f0 + red_acc[1][c] * f1 + red_acc[2][c] * f2 + red_acc[3][c] * f3;
        gs[c] = aa / (ss + 1e-16f) + gbias[c];
    }
    __syncthreads();

    // MLP layer 1: g[256] -> u[64]
    float a1 = 0.f;
    for (int k = w * 64; k < w * 64 + 64; ++k) a1 += gs[k] * W1[k * DIM + l];
    part[t] = a1;
    __syncthreads();
    if (t < DIM)
        us[t] = fmaxf(part[t] + part[64 + t] + part[128 + t] + part[192 + t] + b1[t], 0.f);
    __syncthreads();

    // MLP layer 2: u[64] -> hn[64]
    float a2 = 0.f;
    for (int k = w * 16; k < w * 16 + 16; ++k) a2 += us[k] * W2[k * DIM + l];
    part[t] = a2;
    __syncthreads();
    if (t < DIM)
        hns[t] = part[t] + part[64 + t] + part[128 + t] + part[192 + t] + b2[t];
    __syncthreads();

    // ACT halting (wave 0)
    if (w == 0) {
        float p = hns[l] * actW[l];
        #pragma unroll
        for (int mo = 32; mo; mo >>= 1) p += __shfl_xor(p, mo, 64);
        if (l == 0) {
            float term = 1.f / (1.f + __expf(-(p + actB[0])));
            float tot = act_total[n];
            float nt = fminf(tot + term, 1.f);
            float dl = fminf(term, nt - tot);
            act_total[n] = tot + dl;
            delta_s = dl;
        }
    }
    __syncthreads();
    if (t < DIM) {
        float hv = hns[t];
        final_[n * DIM + t] += delta_s * hv;
        h[n * DIM + t] = hv;
    }
}

// ---------------- decoder + log_softmax ----------------
__global__ void decoder_kernel(const float* __restrict__ final_,
                               const float* __restrict__ decW, const float* __restrict__ decB,
                               const int* __restrict__ flags, void* __restrict__ outv) {
    int id = blockIdx.x * 256 + threadIdx.x;
    if (id >= N_NODES * N_PRED * N_CLASS) return;
    int n = id >> 5, r = id & 31, p = r >> 4, c = r & 15;
    float acc = decB[p * N_CLASS + c];
    for (int dd = 0; dd < DIM; ++dd)
        acc += final_[n * DIM + dd] * decW[(p * DIM + dd) * N_CLASS + c];
    float mx = acc;
    #pragma unroll
    for (int mo = 8; mo; mo >>= 1) mx = fmaxf(mx, __shfl_xor(mx, mo, 64));
    float ex = __expf(acc - mx);
    float ss = ex;
    #pragma unroll
    for (int mo = 8; mo; mo >>= 1) ss += __shfl_xor(ss, mo, 64);
    float ov = acc - mx - logf(ss);
    int oi = p * (N_NODES * N_CLASS) + n * N_CLASS + c;
    if (flags[1]) ((bf16*)outv)[oi] = __float2bfloat16(ov);
    else          ((float*)outv)[oi] = ov;
}

// ---------------- host launcher ----------------
static size_t align256(size_t x) { return (x + 255) & ~size_t(255); }

extern "C" void kernel_launch(void* const* d_in, const int* in_sizes, int n_in,
                              void* d_out, int out_size, void* d_ws, size_t ws_size,
                              hipStream_t stream) {
    const int* edges = (const int*)d_in[1];

    static const int fids[17] = {0, 2, 3, 4, 5, 6, 7, 8, 9, 10, 11, 12, 13, 14, 15, 16, 17};
    ConvTable tab;
    int cum = 0;
    for (int i = 0; i < 17; ++i) {
        tab.src[i] = d_in[fids[i]];
        tab.start[i] = cum;
        cum += in_sizes[fids[i]];
    }
    tab.start[17] = cum;

    // workspace carve-up (~30 MB)
    char* w = (char*)d_ws;
    size_t o = 0;
    int* flags     = (int*)(w + o); o = align256(o + 16 * sizeof(int));
    int* off       = (int*)(w + o); o = align256(o + (N_NODES + 1) * sizeof(int));
    int* deg       = (int*)(w + o); o = align256(o + N_NODES * sizeof(int));
    int* cursor    = (int*)(w + o); o = align256(o + N_NODES * sizeof(int));
    int* csr_src   = (int*)(w + o); o = align256(o + N_E2 * sizeof(int));
    float* xf      = (float*)(w + o); o = align256(o + (size_t)cum * sizeof(float));
    float* h       = (float*)(w + o); o = align256(o + (size_t)N_NODES * DIM * sizeof(float));
    float* xl      = (float*)(w + o); o = align256(o + (size_t)N_NODES * HD * sizeof(float));
    float* xr      = (float*)(w + o); o = align256(o + (size_t)N_NODES * HD * sizeof(float));
    float* act_tot = (float*)(w + o); o = align256(o + N_NODES * sizeof(float));
    float* final_  = (float*)(w + o); o = align256(o + (size_t)N_NODES * DIM * sizeof(float));
    if (o > ws_size) return;  // diagnostic: zero output => ws too small

    const float* Xf   = xf + tab.start[0];
    const float* encW = xf + tab.start[1];
    const float* encB = xf + tab.start[2];
    const float* Wl   = xf + tab.start[3];
    const float* bl   = xf + tab.start[4];
    const float* Wr   = xf + tab.start[5];
    const float* br   = xf + tab.start[6];
    const float* att  = xf + tab.start[7];
    const float* gbias= xf + tab.start[8];
    const float* W1   = xf + tab.start[9];
    const float* b1   = xf + tab.start[10];
    const float* W2   = xf + tab.start[11];
    const float* b2   = xf + tab.start[12];
    const float* actW = xf + tab.start[13];
    const float* actB = xf + tab.start[14];
    const float* decW = xf + tab.start[15];
    const float* decB = xf + tab.start[16];

    hipMemsetAsync(deg,     0, N_NODES * sizeof(int), stream);
    hipMemsetAsync(cursor,  0, N_NODES * sizeof(int), stream);
    hipMemsetAsync(act_tot, 0, N_NODES * sizeof(float), stream);
    hipMemsetAsync(final_,  0, (size_t)N_NODES * DIM * sizeof(float), stream);

    detect_kernel<<<1, 256, 0, stream>>>((const unsigned int*)d_in[1],
                                         (const unsigned short*)d_in[0], flags);
    convert_kernel<<<(cum + 255) / 256, 256, 0, stream>>>(tab, flags, xf);

    int eb = (N_E2 + 255) / 256;
    hist_kernel<<<eb, 256, 0, stream>>>(edges, flags, deg);
    scan_kernel<<<1, 1024, 0, stream>>>(deg, off);
    scatter_kernel<<<eb, 256, 0, stream>>>(edges, flags, off, cursor, csr_src);

    encoder_kernel<<<N_NODES / 4, 256, 0, stream>>>(Xf, encW, encB, h);

    for (int step = 0; step < N_STEPS; ++step) {
        proj_kernel<<<N_NODES / 8, 256, 0, stream>>>(h, Wl, bl, Wr, br, xl, xr);
        node_fused_kernel<<<N_NODES, 256, 0, stream>>>(
            h, xl, xr, att, gbias, W1, b1, W2, b2, actW, actB,
            off, csr_src, act_tot, final_);
    }

    int db = (N_NODES * N_PRED * N_CLASS + 255) / 256;
    decoder_kernel<<<db, 256, 0, stream>>>(final_, decW, decB, flags, d_out);
}

// Round 5
// 472.502 us; speedup vs baseline: 3.7663x; 1.0456x over previous
//
#include <hip/hip_runtime.h>
#include <hip/hip_bf16.h>
#include <hip/hip_fp16.h>

#define N_NODES 10000
#define N_EDGES 160000
#define N_E2    (N_EDGES + N_NODES)   // with self-loops
#define DIM     64
#define HD      256                    // HEADS * DIM
#define N_PRED  2
#define N_CLASS 16
#define N_STEPS 4

typedef __hip_bfloat16 bf16;
__device__ __forceinline__ float b2f(bf16 v) { return __bfloat162float(v); }
__device__ __forceinline__ int clampn(int v) { return v < 0 ? 0 : (v >= N_NODES ? N_NODES - 1 : v); }

struct ConvTable {
    const void* src[17];
    int start[18];   // prefix offsets into xf; start[17] = total
};

// ---------------- dtype detection (1 block) ----------------
__global__ void detect_kernel(const unsigned int* __restrict__ e32,
                              const unsigned short* __restrict__ x16,
                              int* __restrict__ flags) {
    __shared__ int ce, cf;
    if (threadIdx.x == 0) { ce = 0; cf = 0; }
    __syncthreads();
    int le = 0;
    for (int i = threadIdx.x; i < 2048; i += 256)
        le += (e32[2 * i + 1] != 0u) ? 1 : 0;
    int lf = 0;
    for (int i = threadIdx.x; i < 1024; i += 256) {
        unsigned short u = x16[2 * i];
        int ex = (u >> 7) & 0xFF;
        lf += (u == 0 || (ex >= 114 && ex <= 141)) ? 1 : 0;
    }
    atomicAdd(&ce, le);
    atomicAdd(&cf, lf);
    __syncthreads();
    if (threadIdx.x == 0) {
        flags[0] = (ce < 1024) ? 1 : 0;   // edge_index is int64
        flags[1] = (cf >= 512) ? 1 : 0;   // floats are bf16
    }
}

// ---------------- normalize all float inputs to fp32 in workspace ----------------
__global__ void convert_kernel(ConvTable tab, const int* __restrict__ flags,
                               float* __restrict__ xf) {
    int i = blockIdx.x * 256 + threadIdx.x;
    if (i >= tab.start[17]) return;
    int j = 0;
    #pragma unroll
    for (int k = 1; k < 17; ++k) j += (i >= tab.start[k]) ? 1 : 0;
    int off = i - tab.start[j];
    float v;
    if (flags[1]) v = b2f(((const bf16*)tab.src[j])[off]);
    else          v = ((const float*)tab.src[j])[off];
    xf[i] = v;
}

// ---------------- CSR by dst ----------------
__global__ void hist_kernel(const int* __restrict__ edges, const int* __restrict__ flags,
                            int* __restrict__ deg) {
    int e = blockIdx.x * 256 + threadIdx.x;
    if (e >= N_E2) return;
    int i64 = flags[0];
    int dst;
    if (e < N_EDGES) dst = clampn(i64 ? edges[2 * (N_EDGES + e)] : edges[N_EDGES + e]);
    else             dst = e - N_EDGES;
    atomicAdd(&deg[dst], 1);
}

__global__ void scan_kernel(const int* __restrict__ deg, int* __restrict__ off) {
    __shared__ int partial[1024];
    const int tid = threadIdx.x;
    const int per = (N_NODES + 1023) / 1024;  // 10
    int local[16];
    int base = tid * per;
    int s = 0;
    for (int i = 0; i < per; ++i) {
        int v = (base + i < N_NODES) ? deg[base + i] : 0;
        local[i] = s;
        s += v;
    }
    partial[tid] = s;
    __syncthreads();
    for (int d = 1; d < 1024; d <<= 1) {
        int t = (tid >= d) ? partial[tid - d] : 0;
        __syncthreads();
        partial[tid] += t;
        __syncthreads();
    }
    int offset = (tid > 0) ? partial[tid - 1] : 0;
    for (int i = 0; i < per; ++i)
        if (base + i < N_NODES) off[base + i] = offset + local[i];
    if (tid == 1023) off[N_NODES] = partial[1023];
}

__global__ void scatter_kernel(const int* __restrict__ edges, const int* __restrict__ flags,
                               const int* __restrict__ off, int* __restrict__ cursor,
                               int* __restrict__ csr_src) {
    int e = blockIdx.x * 256 + threadIdx.x;
    if (e >= N_E2) return;
    int i64 = flags[0];
    int src, dst;
    if (e < N_EDGES) {
        src = clampn(i64 ? edges[2 * e] : edges[e]);
        dst = clampn(i64 ? edges[2 * (N_EDGES + e)] : edges[N_EDGES + e]);
    } else { src = dst = e - N_EDGES; }
    int pos = off[dst] + atomicAdd(&cursor[dst], 1);
    csr_src[pos] = src;
}

// ---------------- encoder: h0 = x @ enc_W + enc_b ----------------
__global__ void encoder_kernel(const float* __restrict__ x, const float* __restrict__ W,
                               const float* __restrict__ b, float* __restrict__ h) {
    __shared__ float xs[4][DIM];
    int g = threadIdx.x >> 6, d = threadIdx.x & 63;
    int n = blockIdx.x * 4 + g;
    xs[g][d] = x[n * DIM + d];
    __syncthreads();
    float acc = b[d];
    #pragma unroll 8
    for (int k = 0; k < DIM; ++k) acc += xs[g][k] * W[k * DIM + d];
    h[n * DIM + d] = acc;
}

// ---------------- projections: xl (fp16) AND xr (fp32), 8 nodes/block ----------------
__global__ __launch_bounds__(256) void proj_kernel(
        const float* __restrict__ h,
        const float* __restrict__ Wl, const float* __restrict__ bl,
        const float* __restrict__ Wr, const float* __restrict__ br,
        __half* __restrict__ xlh, float* __restrict__ xr) {
    __shared__ float xs[8][DIM];
    int t = threadIdx.x;
    int n0 = blockIdx.x * 8;
    xs[t >> 6][t & 63]       = h[n0 * DIM + t];
    xs[4 + (t >> 6)][t & 63] = h[(n0 + 4) * DIM + t];
    __syncthreads();
    float al[8] = {0,0,0,0,0,0,0,0};
    float ar[8] = {0,0,0,0,0,0,0,0};
    for (int k = 0; k < DIM; ++k) {
        float wl = Wl[k * HD + t];
        float wr = Wr[k * HD + t];
        #pragma unroll
        for (int j = 0; j < 8; ++j) { al[j] += xs[j][k] * wl; ar[j] += xs[j][k] * wr; }
    }
    float bbl = bl[t], bbr = br[t];
    #pragma unroll
    for (int j = 0; j < 8; ++j) {
        xlh[(n0 + j) * HD + t] = __float2half(al[j] + bbl);
        xr[(n0 + j) * HD + t] = ar[j] + bbr;
    }
}

// ---------------- fused node kernel: logits + flash softmax-agg + MLP + ACT ----------
// block = 1 node; 4 waves walk interleaved edge subsets with private online-softmax
// state; one fp16 xl-row gather (512 B) serves both logit and aggregation.
// 2-deep software pipeline keeps 2 row-gathers in flight per wave.
__global__ __launch_bounds__(256) void node_fused_kernel(
        float* __restrict__ h, const __half* __restrict__ xlh, const float* __restrict__ xr,
        const float* __restrict__ att, const float* __restrict__ gbias,
        const float* __restrict__ W1, const float* __restrict__ b1,
        const float* __restrict__ W2, const float* __restrict__ b2,
        const float* __restrict__ actW, const float* __restrict__ actB,
        const int* __restrict__ off, const int* __restrict__ csr_src,
        float* __restrict__ act_total, float* __restrict__ final_) {
    __shared__ float red_m[4][4];     // [wave][head]
    __shared__ float red_s[4][4];
    __shared__ float red_acc[4][HD];  // [wave][channel]  4 KB
    __shared__ float gs[HD];
    __shared__ float part[256];
    __shared__ float us[DIM];
    __shared__ float hns[DIM];
    __shared__ float delta_s;
    int n = blockIdx.x;
    int t = threadIdx.x, w = t >> 6, l = t & 63;
    int e0 = off[n], e1 = off[n + 1];

    // block-uniform per-node data: lane l holds channels [4l, 4l+4)
    const float4 xr4 = ((const float4*)(xr + (size_t)n * HD))[l];
    const float4 at4 = ((const float4*)att)[l];

    // edge phase: wave w handles edges e0+w, e0+w+4, ... with online softmax
    float m = -1e30f, s = 0.f;
    float4 acc = {0.f, 0.f, 0.f, 0.f};
    const uint2 zero2 = {0u, 0u};
    int e = e0 + w;
    uint2 r0 = zero2, r1 = zero2;
    if (e < e1)
        r0 = ((const uint2*)(xlh + (size_t)csr_src[e] * HD))[l];
    if (e + 4 < e1)
        r1 = ((const uint2*)(xlh + (size_t)csr_src[e + 4] * HD))[l];
    for (; e < e1; e += 4) {
        uint2 cur = r0;
        r0 = r1;
        if (e + 8 < e1)
            r1 = ((const uint2*)(xlh + (size_t)csr_src[e + 8] * HD))[l];
        // unpack 4 fp16 channels -> fp32
        __half2 h01 = *reinterpret_cast<__half2*>(&cur.x);
        __half2 h23 = *reinterpret_cast<__half2*>(&cur.y);
        float2 f01 = __half22float2(h01);
        float2 f23 = __half22float2(h23);
        float c0 = f01.x, c1 = f01.y, c2 = f23.x, c3 = f23.y;
        float z0 = c0 + xr4.x, z1 = c1 + xr4.y, z2 = c2 + xr4.z, z3 = c3 + xr4.w;
        z0 = (z0 > 0.f) ? z0 : 0.2f * z0;
        z1 = (z1 > 0.f) ? z1 : 0.2f * z1;
        z2 = (z2 > 0.f) ? z2 : 0.2f * z2;
        z3 = (z3 > 0.f) ? z3 : 0.2f * z3;
        float p = z0 * at4.x + z1 * at4.y + z2 * at4.z + z3 * at4.w;
        #pragma unroll
        for (int mo = 8; mo; mo >>= 1) p += __shfl_xor(p, mo, 64);  // 16-lane head reduce
        float nm = fmaxf(m, p);
        float sc = __expf(m - nm);
        float wv = __expf(p - nm);
        s = s * sc + wv;
        acc.x = acc.x * sc + wv * c0;
        acc.y = acc.y * sc + wv * c1;
        acc.z = acc.z * sc + wv * c2;
        acc.w = acc.w * sc + wv * c3;
        m = nm;
    }
    // publish per-wave state
    if ((l & 15) == 0) { red_m[w][l >> 4] = m; red_s[w][l >> 4] = s; }
    ((float4*)red_acc[w])[l] = acc;
    __syncthreads();

    // flash-merge the 4 wave-partials: thread t = channel c
    {
        int c = t, hh = c >> 6;
        float m0 = red_m[0][hh], m1 = red_m[1][hh], m2 = red_m[2][hh], m3 = red_m[3][hh];
        float mm = fmaxf(fmaxf(m0, m1), fmaxf(m2, m3));
        float f0 = __expf(m0 - mm), f1 = __expf(m1 - mm),
              f2 = __expf(m2 - mm), f3 = __expf(m3 - mm);
        float ss = red_s[0][hh] * f0 + red_s[1][hh] * f1 + red_s[2][hh] * f2 + red_s[3][hh] * f3;
        float aa = red_acc[0][c] * f0 + red_acc[1][c] * f1 + red_acc[2][c] * f2 + red_acc[3][c] * f3;
        gs[c] = aa / (ss + 1e-16f) + gbias[c];
    }
    __syncthreads();

    // MLP layer 1: g[256] -> u[64]
    float a1 = 0.f;
    for (int k = w * 64; k < w * 64 + 64; ++k) a1 += gs[k] * W1[k * DIM + l];
    part[t] = a1;
    __syncthreads();
    if (t < DIM)
        us[t] = fmaxf(part[t] + part[64 + t] + part[128 + t] + part[192 + t] + b1[t], 0.f);
    __syncthreads();

    // MLP layer 2: u[64] -> hn[64]
    float a2 = 0.f;
    for (int k = w * 16; k < w * 16 + 16; ++k) a2 += us[k] * W2[k * DIM + l];
    part[t] = a2;
    __syncthreads();
    if (t < DIM)
        hns[t] = part[t] + part[64 + t] + part[128 + t] + part[192 + t] + b2[t];
    __syncthreads();

    // ACT halting (wave 0)
    if (w == 0) {
        float p = hns[l] * actW[l];
        #pragma unroll
        for (int mo = 32; mo; mo >>= 1) p += __shfl_xor(p, mo, 64);
        if (l == 0) {
            float term = 1.f / (1.f + __expf(-(p + actB[0])));
            float tot = act_total[n];
            float nt = fminf(tot + term, 1.f);
            float dl = fminf(term, nt - tot);
            act_total[n] = tot + dl;
            delta_s = dl;
        }
    }
    __syncthreads();
    if (t < DIM) {
        float hv = hns[t];
        final_[n * DIM + t] += delta_s * hv;
        h[n * DIM + t] = hv;
    }
}

// ---------------- decoder + log_softmax ----------------
__global__ void decoder_kernel(const float* __restrict__ final_,
                               const float* __restrict__ decW, const float* __restrict__ decB,
                               const int* __restrict__ flags, void* __restrict__ outv) {
    int id = blockIdx.x * 256 + threadIdx.x;
    if (id >= N_NODES * N_PRED * N_CLASS) return;
    int n = id >> 5, r = id & 31, p = r >> 4, c = r & 15;
    float acc = decB[p * N_CLASS + c];
    for (int dd = 0; dd < DIM; ++dd)
        acc += final_[n * DIM + dd] * decW[(p * DIM + dd) * N_CLASS + c];
    float mx = acc;
    #pragma unroll
    for (int mo = 8; mo; mo >>= 1) mx = fmaxf(mx, __shfl_xor(mx, mo, 64));
    float ex = __expf(acc - mx);
    float ss = ex;
    #pragma unroll
    for (int mo = 8; mo; mo >>= 1) ss += __shfl_xor(ss, mo, 64);
    float ov = acc - mx - logf(ss);
    int oi = p * (N_NODES * N_CLASS) + n * N_CLASS + c;
    if (flags[1]) ((bf16*)outv)[oi] = __float2bfloat16(ov);
    else          ((float*)outv)[oi] = ov;
}

// ---------------- host launcher ----------------
static size_t align256(size_t x) { return (x + 255) & ~size_t(255); }

extern "C" void kernel_launch(void* const* d_in, const int* in_sizes, int n_in,
                              void* d_out, int out_size, void* d_ws, size_t ws_size,
                              hipStream_t stream) {
    const int* edges = (const int*)d_in[1];

    static const int fids[17] = {0, 2, 3, 4, 5, 6, 7, 8, 9, 10, 11, 12, 13, 14, 15, 16, 17};
    ConvTable tab;
    int cum = 0;
    for (int i = 0; i < 17; ++i) {
        tab.src[i] = d_in[fids[i]];
        tab.start[i] = cum;
        cum += in_sizes[fids[i]];
    }
    tab.start[17] = cum;

    // workspace carve-up.  Zero-init region is contiguous: [deg cursor act_tot final_]
    char* w = (char*)d_ws;
    size_t o = 0;
    int* flags     = (int*)(w + o); o = align256(o + 16 * sizeof(int));
    int* off       = (int*)(w + o); o = align256(o + (N_NODES + 1) * sizeof(int));
    size_t zbase = o;
    int* deg       = (int*)(w + o); o = align256(o + N_NODES * sizeof(int));
    int* cursor    = (int*)(w + o); o = align256(o + N_NODES * sizeof(int));
    float* act_tot = (float*)(w + o); o = align256(o + N_NODES * sizeof(float));
    float* final_  = (float*)(w + o); o = align256(o + (size_t)N_NODES * DIM * sizeof(float));
    size_t zsize = o - zbase;
    int* csr_src   = (int*)(w + o); o = align256(o + N_E2 * sizeof(int));
    float* xf      = (float*)(w + o); o = align256(o + (size_t)cum * sizeof(float));
    float* h       = (float*)(w + o); o = align256(o + (size_t)N_NODES * DIM * sizeof(float));
    __half* xlh    = (__half*)(w + o); o = align256(o + (size_t)N_NODES * HD * sizeof(__half));
    float* xr      = (float*)(w + o); o = align256(o + (size_t)N_NODES * HD * sizeof(float));
    if (o > ws_size) return;  // diagnostic: zero output => ws too small

    const float* Xf   = xf + tab.start[0];
    const float* encW = xf + tab.start[1];
    const float* encB = xf + tab.start[2];
    const float* Wl   = xf + tab.start[3];
    const float* bl   = xf + tab.start[4];
    const float* Wr   = xf + tab.start[5];
    const float* br   = xf + tab.start[6];
    const float* att  = xf + tab.start[7];
    const float* gbias= xf + tab.start[8];
    const float* W1   = xf + tab.start[9];
    const float* b1   = xf + tab.start[10];
    const float* W2   = xf + tab.start[11];
    const float* b2   = xf + tab.start[12];
    const float* actW = xf + tab.start[13];
    const float* actB = xf + tab.start[14];
    const float* decW = xf + tab.start[15];
    const float* decB = xf + tab.start[16];

    hipMemsetAsync(w + zbase, 0, zsize, stream);   // deg, cursor, act_tot, final_

    detect_kernel<<<1, 256, 0, stream>>>((const unsigned int*)d_in[1],
                                         (const unsigned short*)d_in[0], flags);
    convert_kernel<<<(cum + 255) / 256, 256, 0, stream>>>(tab, flags, xf);

    int eb = (N_E2 + 255) / 256;
    hist_kernel<<<eb, 256, 0, stream>>>(edges, flags, deg);
    scan_kernel<<<1, 1024, 0, stream>>>(deg, off);
    scatter_kernel<<<eb, 256, 0, stream>>>(edges, flags, off, cursor, csr_src);

    encoder_kernel<<<N_NODES / 4, 256, 0, stream>>>(Xf, encW, encB, h);

    for (int step = 0; step < N_STEPS; ++step) {
        proj_kernel<<<N_NODES / 8, 256, 0, stream>>>(h, Wl, bl, Wr, br, xlh, xr);
        node_fused_kernel<<<N_NODES, 256, 0, stream>>>(
            h, xlh, xr, att, gbias, W1, b1, W2, b2, actW, actB,
            off, csr_src, act_tot, final_);
    }

    int db = (N_NODES * N_PRED * N_CLASS + 255) / 256;
    decoder_kernel<<<db, 256, 0, stream>>>(final_, decW, decB, flags, d_out);
}

// Round 7
// 398.225 us; speedup vs baseline: 4.4688x; 1.1865x over previous
//
#include <hip/hip_runtime.h>
#include <hip/hip_bf16.h>
#include <hip/hip_fp16.h>

#define N_NODES 10000
#define N_EDGES 160000
#define N_E2    (N_EDGES + N_NODES)   // with self-loops
#define DIM     64
#define HD      256                    // HEADS * DIM
#define N_PRED  2
#define N_CLASS 16
#define N_STEPS 4

typedef __hip_bfloat16 bf16;
__device__ __forceinline__ float b2f(bf16 v) { return __bfloat162float(v); }
__device__ __forceinline__ int clampn(int v) { return v < 0 ? 0 : (v >= N_NODES ? N_NODES - 1 : v); }

struct ConvTable {
    const void* src[17];
    int start[18];
};

// ---------------- dtype detection (1 block) ----------------
__global__ void detect_kernel(const unsigned int* __restrict__ e32,
                              const unsigned short* __restrict__ x16,
                              int* __restrict__ flags) {
    __shared__ int ce, cf;
    if (threadIdx.x == 0) { ce = 0; cf = 0; }
    __syncthreads();
    int le = 0;
    for (int i = threadIdx.x; i < 2048; i += 256)
        le += (e32[2 * i + 1] != 0u) ? 1 : 0;
    int lf = 0;
    for (int i = threadIdx.x; i < 1024; i += 256) {
        unsigned short u = x16[2 * i];
        int ex = (u >> 7) & 0xFF;
        lf += (u == 0 || (ex >= 114 && ex <= 141)) ? 1 : 0;
    }
    atomicAdd(&ce, le);
    atomicAdd(&cf, lf);
    __syncthreads();
    if (threadIdx.x == 0) {
        flags[0] = (ce < 1024) ? 1 : 0;   // edge_index is int64
        flags[1] = (cf >= 512) ? 1 : 0;   // floats are bf16
    }
}

// ---------------- normalize all float inputs to fp32 in workspace ----------------
__global__ void convert_kernel(ConvTable tab, const int* __restrict__ flags,
                               float* __restrict__ xf) {
    int i = blockIdx.x * 256 + threadIdx.x;
    if (i >= tab.start[17]) return;
    int j = 0;
    #pragma unroll
    for (int k = 1; k < 17; ++k) j += (i >= tab.start[k]) ? 1 : 0;
    int off = i - tab.start[j];
    float v;
    if (flags[1]) v = b2f(((const bf16*)tab.src[j])[off]);
    else          v = ((const float*)tab.src[j])[off];
    xf[i] = v;
}

// ---------------- CSR by dst ----------------
__global__ void hist_kernel(const int* __restrict__ edges, const int* __restrict__ flags,
                            int* __restrict__ deg) {
    int e = blockIdx.x * 256 + threadIdx.x;
    if (e >= N_E2) return;
    int i64 = flags[0];
    int dst;
    if (e < N_EDGES) dst = clampn(i64 ? edges[2 * (N_EDGES + e)] : edges[N_EDGES + e]);
    else             dst = e - N_EDGES;
    atomicAdd(&deg[dst], 1);
}

__global__ void scan_kernel(const int* __restrict__ deg, int* __restrict__ off) {
    __shared__ int partial[1024];
    const int tid = threadIdx.x;
    const int per = (N_NODES + 1023) / 1024;  // 10
    int local[16];
    int base = tid * per;
    int s = 0;
    for (int i = 0; i < per; ++i) {
        int v = (base + i < N_NODES) ? deg[base + i] : 0;
        local[i] = s;
        s += v;
    }
    partial[tid] = s;
    __syncthreads();
    for (int d = 1; d < 1024; d <<= 1) {
        int t = (tid >= d) ? partial[tid - d] : 0;
        __syncthreads();
        partial[tid] += t;
        __syncthreads();
    }
    int offset = (tid > 0) ? partial[tid - 1] : 0;
    for (int i = 0; i < per; ++i)
        if (base + i < N_NODES) off[base + i] = offset + local[i];
    if (tid == 1023) off[N_NODES] = partial[1023];
}

__global__ void scatter_kernel(const int* __restrict__ edges, const int* __restrict__ flags,
                               const int* __restrict__ off, int* __restrict__ cursor,
                               int* __restrict__ csr_src) {
    int e = blockIdx.x * 256 + threadIdx.x;
    if (e >= N_E2) return;
    int i64 = flags[0];
    int src, dst;
    if (e < N_EDGES) {
        src = clampn(i64 ? edges[2 * e] : edges[e]);
        dst = clampn(i64 ? edges[2 * (N_EDGES + e)] : edges[N_EDGES + e]);
    } else { src = dst = e - N_EDGES; }
    int pos = off[dst] + atomicAdd(&cursor[dst], 1);
    csr_src[pos] = src;
}

// ---------------- encoder + step-0 projections (8 nodes/block) ----------------
__global__ __launch_bounds__(256) void enc_proj_kernel(
        const float* __restrict__ Xf,
        const float* __restrict__ encW, const float* __restrict__ encB,
        const float* __restrict__ Wl, const float* __restrict__ bl,
        const float* __restrict__ Wr, const float* __restrict__ br,
        __half* __restrict__ xlh, float* __restrict__ xr) {
    __shared__ float xs[8][DIM];
    __shared__ float h0[8][DIM];
    const int t = threadIdx.x, pp = t >> 6, d = t & 63;
    const int n0 = blockIdx.x * 8;
    ((float*)xs)[t]       = Xf[n0 * DIM + t];
    ((float*)xs)[t + 256] = Xf[n0 * DIM + t + 256];
    __syncthreads();
    float ah0 = encB[d], ah1 = encB[d];
    for (int k = 0; k < DIM; ++k) {
        float wv = encW[k * DIM + d];
        ah0 += xs[pp][k] * wv;
        ah1 += xs[pp + 4][k] * wv;
    }
    h0[pp][d]     = ah0;
    h0[pp + 4][d] = ah1;
    __syncthreads();
    float al[8] = {0,0,0,0,0,0,0,0}, ar[8] = {0,0,0,0,0,0,0,0};
    for (int k = 0; k < DIM; ++k) {
        float wl = Wl[k * HD + t], wr = Wr[k * HD + t];
        #pragma unroll
        for (int j = 0; j < 8; ++j) { al[j] += h0[j][k] * wl; ar[j] += h0[j][k] * wr; }
    }
    float bbl = bl[t], bbr = br[t];
    #pragma unroll
    for (int j = 0; j < 8; ++j) {
        xlh[(size_t)(n0 + j) * HD + t] = __float2half(al[j] + bbl);
        xr[(size_t)(n0 + j) * HD + t] = ar[j] + bbr;
    }
}

// ---------------- edge flash softmax-agg (block = node) -> gbuf ----------------
__global__ __launch_bounds__(256) void edge_agg_kernel(
        const __half* __restrict__ xlh, const float* __restrict__ xr,
        const float* __restrict__ att, const float* __restrict__ gbias,
        const int* __restrict__ off, const int* __restrict__ csr_src,
        float* __restrict__ gbuf) {
    __shared__ float red_m[4][4];
    __shared__ float red_s[4][4];
    __shared__ float red_acc[4][HD];
    const int n = blockIdx.x;
    const int t = threadIdx.x, w = t >> 6, l = t & 63;
    const int e0 = off[n], e1 = off[n + 1];
    const float4 xr4 = ((const float4*)(xr + (size_t)n * HD))[l];
    const float4 at4 = ((const float4*)att)[l];

    float m = -1e30f, s = 0.f;
    float4 acc = {0.f, 0.f, 0.f, 0.f};
    const uint2 zero2 = {0u, 0u};
    int e = e0 + w;
    uint2 r0 = zero2, r1 = zero2;
    if (e < e1)     r0 = ((const uint2*)(xlh + (size_t)csr_src[e] * HD))[l];
    if (e + 4 < e1) r1 = ((const uint2*)(xlh + (size_t)csr_src[e + 4] * HD))[l];
    for (; e < e1; e += 4) {
        uint2 cur = r0;
        r0 = r1;
        if (e + 8 < e1)
            r1 = ((const uint2*)(xlh + (size_t)csr_src[e + 8] * HD))[l];
        __half2 h01 = *reinterpret_cast<__half2*>(&cur.x);
        __half2 h23 = *reinterpret_cast<__half2*>(&cur.y);
        float2 f01 = __half22float2(h01);
        float2 f23 = __half22float2(h23);
        float c0 = f01.x, c1 = f01.y, c2 = f23.x, c3 = f23.y;
        float z0 = c0 + xr4.x, z1 = c1 + xr4.y, z2 = c2 + xr4.z, z3 = c3 + xr4.w;
        z0 = (z0 > 0.f) ? z0 : 0.2f * z0;
        z1 = (z1 > 0.f) ? z1 : 0.2f * z1;
        z2 = (z2 > 0.f) ? z2 : 0.2f * z2;
        z3 = (z3 > 0.f) ? z3 : 0.2f * z3;
        float p = z0 * at4.x + z1 * at4.y + z2 * at4.z + z3 * at4.w;
        #pragma unroll
        for (int mo = 8; mo; mo >>= 1) p += __shfl_xor(p, mo, 64);
        float nm = fmaxf(m, p);
        float sc = __expf(m - nm);
        float wv = __expf(p - nm);
        s = s * sc + wv;
        acc.x = acc.x * sc + wv * c0;
        acc.y = acc.y * sc + wv * c1;
        acc.z = acc.z * sc + wv * c2;
        acc.w = acc.w * sc + wv * c3;
        m = nm;
    }
    if ((l & 15) == 0) { red_m[w][l >> 4] = m; red_s[w][l >> 4] = s; }
    ((float4*)red_acc[w])[l] = acc;
    __syncthreads();
    {
        int hh = t >> 6;
        float m0 = red_m[0][hh], m1 = red_m[1][hh], m2 = red_m[2][hh], m3 = red_m[3][hh];
        float mm = fmaxf(fmaxf(m0, m1), fmaxf(m2, m3));
        float f0 = __expf(m0 - mm), f1 = __expf(m1 - mm),
              f2 = __expf(m2 - mm), f3 = __expf(m3 - mm);
        float ss = red_s[0][hh] * f0 + red_s[1][hh] * f1 +
                   red_s[2][hh] * f2 + red_s[3][hh] * f3;
        float aa = red_acc[0][t] * f0 + red_acc[1][t] * f1 +
                   red_acc[2][t] * f2 + red_acc[3][t] * f3;
        gbuf[(size_t)n * HD + t] = aa / (ss + 1e-16f) + gbias[t];
    }
}

// ---------------- MLP + ACT + next-step projections (8 nodes/block) ----------------
__global__ __launch_bounds__(256) void mlp_act_proj_kernel(
        const float* __restrict__ gbuf,
        const float* __restrict__ W1, const float* __restrict__ b1,
        const float* __restrict__ W2, const float* __restrict__ b2,
        const float* __restrict__ actW, const float* __restrict__ actB,
        const float* __restrict__ Wl, const float* __restrict__ bl,
        const float* __restrict__ Wr, const float* __restrict__ br,
        float* __restrict__ act_tot, float* __restrict__ final_,
        __half* __restrict__ xlh, float* __restrict__ xr, int do_proj) {
    __shared__ float gall[8][HD];
    __shared__ float part[8][HD];
    __shared__ float us[8][DIM];
    __shared__ float hns[8][DIM];
    __shared__ float delta[8];
    const int t = threadIdx.x, pp = t >> 6, d = t & 63;
    const int n0 = blockIdx.x * 8;

    for (int i = t; i < 8 * HD; i += 256)
        ((float*)gall)[i] = gbuf[(size_t)n0 * HD + i];
    __syncthreads();

    // MLP1: [256] -> [64]
    float acc8[8] = {0,0,0,0,0,0,0,0};
    for (int k = pp * 64; k < pp * 64 + 64; ++k) {
        float wv = W1[k * DIM + d];
        #pragma unroll
        for (int j = 0; j < 8; ++j) acc8[j] += gall[j][k] * wv;
    }
    #pragma unroll
    for (int j = 0; j < 8; ++j) part[j][t] = acc8[j];
    __syncthreads();
    {
        float bb = b1[d];
        float v0 = part[pp][d] + part[pp][64 + d] + part[pp][128 + d] + part[pp][192 + d] + bb;
        float v1 = part[pp + 4][d] + part[pp + 4][64 + d] +
                   part[pp + 4][128 + d] + part[pp + 4][192 + d] + bb;
        us[pp][d]     = fmaxf(v0, 0.f);
        us[pp + 4][d] = fmaxf(v1, 0.f);
    }
    __syncthreads();
    // MLP2: [64] -> [64]
    #pragma unroll
    for (int j = 0; j < 8; ++j) acc8[j] = 0.f;
    for (int k = pp * 16; k < pp * 16 + 16; ++k) {
        float wv = W2[k * DIM + d];
        #pragma unroll
        for (int j = 0; j < 8; ++j) acc8[j] += us[j][k] * wv;
    }
    #pragma unroll
    for (int j = 0; j < 8; ++j) part[j][t] = acc8[j];
    __syncthreads();
    {
        float bb = b2[d];
        hns[pp][d]     = part[pp][d] + part[pp][64 + d] +
                         part[pp][128 + d] + part[pp][192 + d] + bb;
        hns[pp + 4][d] = part[pp + 4][d] + part[pp + 4][64 + d] +
                         part[pp + 4][128 + d] + part[pp + 4][192 + d] + bb;
    }
    __syncthreads();
    // ACT: wave w handles nodes n0+w, n0+w+4
    {
        const int w = pp, l = d;
        float p0 = hns[w][l] * actW[l];
        float p1 = hns[w + 4][l] * actW[l];
        #pragma unroll
        for (int mo = 32; mo; mo >>= 1) {
            p0 += __shfl_xor(p0, mo, 64);
            p1 += __shfl_xor(p1, mo, 64);
        }
        if (l == 0) {
            float ab = actB[0];
            float term0 = 1.f / (1.f + __expf(-(p0 + ab)));
            float tot0 = act_tot[n0 + w];
            float nt0 = fminf(tot0 + term0, 1.f);
            float dl0 = fminf(term0, nt0 - tot0);
            act_tot[n0 + w] = tot0 + dl0;
            delta[w] = dl0;
            float term1 = 1.f / (1.f + __expf(-(p1 + ab)));
            float tot1 = act_tot[n0 + w + 4];
            float nt1 = fminf(tot1 + term1, 1.f);
            float dl1 = fminf(term1, nt1 - tot1);
            act_tot[n0 + w + 4] = tot1 + dl1;
            delta[w + 4] = dl1;
        }
    }
    __syncthreads();
    final_[(size_t)(n0 + pp) * DIM + d]     += delta[pp] * hns[pp][d];
    final_[(size_t)(n0 + pp + 4) * DIM + d] += delta[pp + 4] * hns[pp + 4][d];

    if (do_proj) {
        float al[8] = {0,0,0,0,0,0,0,0}, ar[8] = {0,0,0,0,0,0,0,0};
        for (int k = 0; k < DIM; ++k) {
            float wl = Wl[k * HD + t], wr = Wr[k * HD + t];
            #pragma unroll
            for (int j = 0; j < 8; ++j) {
                al[j] += hns[j][k] * wl;
                ar[j] += hns[j][k] * wr;
            }
        }
        float bbl = bl[t], bbr = br[t];
        #pragma unroll
        for (int j = 0; j < 8; ++j) {
            xlh[(size_t)(n0 + j) * HD + t] = __float2half(al[j] + bbl);
            xr[(size_t)(n0 + j) * HD + t] = ar[j] + bbr;
        }
    }
}

// ---------------- decoder + log_softmax ----------------
__global__ void decoder_kernel(const float* __restrict__ final_,
                               const float* __restrict__ decW, const float* __restrict__ decB,
                               const int* __restrict__ flags, void* __restrict__ outv) {
    int id = blockIdx.x * 256 + threadIdx.x;
    if (id >= N_NODES * N_PRED * N_CLASS) return;
    int n = id >> 5, r = id & 31, p = r >> 4, c = r & 15;
    float acc = decB[p * N_CLASS + c];
    for (int dd = 0; dd < DIM; ++dd)
        acc += final_[(size_t)n * DIM + dd] * decW[(p * DIM + dd) * N_CLASS + c];
    float mx = acc;
    #pragma unroll
    for (int mo = 8; mo; mo >>= 1) mx = fmaxf(mx, __shfl_xor(mx, mo, 64));
    float ex = __expf(acc - mx);
    float ss = ex;
    #pragma unroll
    for (int mo = 8; mo; mo >>= 1) ss += __shfl_xor(ss, mo, 64);
    float ov = acc - mx - logf(ss);
    int oi = p * (N_NODES * N_CLASS) + n * N_CLASS + c;
    if (flags[1]) ((bf16*)outv)[oi] = __float2bfloat16(ov);
    else          ((float*)outv)[oi] = ov;
}

// ---------------- host launcher ----------------
static size_t align256(size_t x) { return (x + 255) & ~size_t(255); }

extern "C" void kernel_launch(void* const* d_in, const int* in_sizes, int n_in,
                              void* d_out, int out_size, void* d_ws, size_t ws_size,
                              hipStream_t stream) {
    const int* edges = (const int*)d_in[1];

    static const int fids[17] = {0, 2, 3, 4, 5, 6, 7, 8, 9, 10, 11, 12, 13, 14, 15, 16, 17};
    ConvTable tab;
    int cum = 0;
    for (int i = 0; i < 17; ++i) {
        tab.src[i] = d_in[fids[i]];
        tab.start[i] = cum;
        cum += in_sizes[fids[i]];
    }
    tab.start[17] = cum;

    // workspace carve-up. Zero region contiguous: [deg cursor act_tot final_]
    char* w = (char*)d_ws;
    size_t o = 0;
    int* flags     = (int*)(w + o); o = align256(o + 16 * sizeof(int));
    int* off       = (int*)(w + o); o = align256(o + (N_NODES + 1) * sizeof(int));
    size_t zbase = o;
    int* deg       = (int*)(w + o); o = align256(o + N_NODES * sizeof(int));
    int* cursor    = (int*)(w + o); o = align256(o + N_NODES * sizeof(int));
    float* act_tot = (float*)(w + o); o = align256(o + N_NODES * sizeof(float));
    float* final_  = (float*)(w + o); o = align256(o + (size_t)N_NODES * DIM * sizeof(float));
    size_t zsize = o - zbase;
    int* csr_src   = (int*)(w + o); o = align256(o + N_E2 * sizeof(int));
    float* xf      = (float*)(w + o); o = align256(o + (size_t)cum * sizeof(float));
    __half* xlh    = (__half*)(w + o); o = align256(o + (size_t)N_NODES * HD * sizeof(__half));
    float* xr      = (float*)(w + o); o = align256(o + (size_t)N_NODES * HD * sizeof(float));
    float* gbuf    = (float*)(w + o); o = align256(o + (size_t)N_NODES * HD * sizeof(float));
    if (o > ws_size) return;  // diagnostic: zero output => ws too small

    const float* Xf   = xf + tab.start[0];
    const float* encW = xf + tab.start[1];
    const float* encB = xf + tab.start[2];
    const float* Wl   = xf + tab.start[3];
    const float* bl   = xf + tab.start[4];
    const float* Wr   = xf + tab.start[5];
    const float* br   = xf + tab.start[6];
    const float* att  = xf + tab.start[7];
    const float* gbias= xf + tab.start[8];
    const float* W1   = xf + tab.start[9];
    const float* b1   = xf + tab.start[10];
    const float* W2   = xf + tab.start[11];
    const float* b2   = xf + tab.start[12];
    const float* actW = xf + tab.start[13];
    const float* actB = xf + tab.start[14];
    const float* decW = xf + tab.start[15];
    const float* decB = xf + tab.start[16];

    hipMemsetAsync(w + zbase, 0, zsize, stream);   // deg, cursor, act_tot, final_

    detect_kernel<<<1, 256, 0, stream>>>((const unsigned int*)d_in[1],
                                         (const unsigned short*)d_in[0], flags);
    convert_kernel<<<(cum + 255) / 256, 256, 0, stream>>>(tab, flags, xf);

    int eb = (N_E2 + 255) / 256;
    hist_kernel<<<eb, 256, 0, stream>>>(edges, flags, deg);
    scan_kernel<<<1, 1024, 0, stream>>>(deg, off);
    scatter_kernel<<<eb, 256, 0, stream>>>(edges, flags, off, cursor, csr_src);

    enc_proj_kernel<<<N_NODES / 8, 256, 0, stream>>>(Xf, encW, encB, Wl, bl, Wr, br, xlh, xr);

    for (int step = 0; step < N_STEPS; ++step) {
        edge_agg_kernel<<<N_NODES, 256, 0, stream>>>(xlh, xr, att, gbias, off, csr_src, gbuf);
        mlp_act_proj_kernel<<<N_NODES / 8, 256, 0, stream>>>(
            gbuf, W1, b1, W2, b2, actW, actB, Wl, bl, Wr, br,
            act_tot, final_, xlh, xr, (step < N_STEPS - 1) ? 1 : 0);
    }

    int db = (N_NODES * N_PRED * N_CLASS + 255) / 256;
    decoder_kernel<<<db, 256, 0, stream>>>(final_, decW, decB, flags, d_out);
}

// Round 8
// 338.906 us; speedup vs baseline: 5.2510x; 1.1750x over previous
//
#include <hip/hip_runtime.h>
#include <hip/hip_bf16.h>
#include <hip/hip_fp16.h>

#define N_NODES 10000
#define N_EDGES 160000
#define N_E2    (N_EDGES + N_NODES)   // with self-loops
#define DIM     64
#define HD      256                    // HEADS * DIM
#define N_PRED  2
#define N_CLASS 16
#define N_STEPS 4

typedef __hip_bfloat16 bf16;
__device__ __forceinline__ float b2f(bf16 v) { return __bfloat162float(v); }
__device__ __forceinline__ int clampn(int v) { return v < 0 ? 0 : (v >= N_NODES ? N_NODES - 1 : v); }

typedef _Float16 h2_t __attribute__((ext_vector_type(2)));

// fp16 pair dot with fp32 accumulate: 1 VALU op for 2 MACs (v_dot2_f32_f16)
__device__ __forceinline__ float dot2(unsigned int a, unsigned int b, float c) {
#if __has_builtin(__builtin_amdgcn_fdot2)
    h2_t av, bv;
    __builtin_memcpy(&av, &a, 4);
    __builtin_memcpy(&bv, &b, 4);
    return __builtin_amdgcn_fdot2(av, bv, c, false);
#else
    __half2 ah = *(__half2*)&a, bh = *(__half2*)&b;
    float2 af = __half22float2(ah), bf = __half22float2(bh);
    return c + af.x * bf.x + af.y * bf.y;
#endif
}

struct ConvTable {
    const void* src[17];
    int start[18];
};

// ---------------- dtype detection (1 block) ----------------
__global__ void detect_kernel(const unsigned int* __restrict__ e32,
                              const unsigned short* __restrict__ x16,
                              int* __restrict__ flags) {
    __shared__ int ce, cf;
    if (threadIdx.x == 0) { ce = 0; cf = 0; }
    __syncthreads();
    int le = 0;
    for (int i = threadIdx.x; i < 2048; i += 256)
        le += (e32[2 * i + 1] != 0u) ? 1 : 0;
    int lf = 0;
    for (int i = threadIdx.x; i < 1024; i += 256) {
        unsigned short u = x16[2 * i];
        int ex = (u >> 7) & 0xFF;
        lf += (u == 0 || (ex >= 114 && ex <= 141)) ? 1 : 0;
    }
    atomicAdd(&ce, le);
    atomicAdd(&cf, lf);
    __syncthreads();
    if (threadIdx.x == 0) {
        flags[0] = (ce < 1024) ? 1 : 0;   // edge_index is int64
        flags[1] = (cf >= 512) ? 1 : 0;   // floats are bf16
    }
}

// ---------------- normalize all float inputs to fp32 in workspace ----------------
__global__ void convert_kernel(ConvTable tab, const int* __restrict__ flags,
                               float* __restrict__ xf) {
    int i = blockIdx.x * 256 + threadIdx.x;
    if (i >= tab.start[17]) return;
    int j = 0;
    #pragma unroll
    for (int k = 1; k < 17; ++k) j += (i >= tab.start[k]) ? 1 : 0;
    int off = i - tab.start[j];
    float v;
    if (flags[1]) v = b2f(((const bf16*)tab.src[j])[off]);
    else          v = ((const float*)tab.src[j])[off];
    xf[i] = v;
}

// ---------------- pack Wl/Wr/W1/W2 into k-paired fp16 half2 layout ----------------
// half2 u32 layout per segment: out[k2*W + c] = (in[2k2][c], in[2k2+1][c])
// offsets (in half2 units): Wlp 0, Wrp 8192, W1p 16384, W2p 24576; total 26624
__global__ void pack_kernel(const float* __restrict__ xf,
                            int oWl, int oWr, int oW1, int oW2,
                            __half* __restrict__ wp) {
    int i = blockIdx.x * 256 + threadIdx.x;
    if (i >= 26624) return;
    int base, width, loc;
    if (i < 8192)       { loc = i;         base = oWl; width = 256; }
    else if (i < 16384) { loc = i - 8192;  base = oWr; width = 256; }
    else if (i < 24576) { loc = i - 16384; base = oW1; width = 64; }
    else                { loc = i - 24576; base = oW2; width = 64; }
    int k2 = loc / width, c = loc % width;
    wp[2 * i]     = __float2half(xf[base + (2 * k2) * width + c]);
    wp[2 * i + 1] = __float2half(xf[base + (2 * k2 + 1) * width + c]);
}

// ---------------- CSR by dst ----------------
__global__ void hist_kernel(const int* __restrict__ edges, const int* __restrict__ flags,
                            int* __restrict__ deg) {
    int e = blockIdx.x * 256 + threadIdx.x;
    if (e >= N_E2) return;
    int i64 = flags[0];
    int dst;
    if (e < N_EDGES) dst = clampn(i64 ? edges[2 * (N_EDGES + e)] : edges[N_EDGES + e]);
    else             dst = e - N_EDGES;
    atomicAdd(&deg[dst], 1);
}

__global__ void scan_kernel(const int* __restrict__ deg, int* __restrict__ off) {
    __shared__ int partial[1024];
    const int tid = threadIdx.x;
    const int per = (N_NODES + 1023) / 1024;  // 10
    int local[16];
    int base = tid * per;
    int s = 0;
    for (int i = 0; i < per; ++i) {
        int v = (base + i < N_NODES) ? deg[base + i] : 0;
        local[i] = s;
        s += v;
    }
    partial[tid] = s;
    __syncthreads();
    for (int d = 1; d < 1024; d <<= 1) {
        int t = (tid >= d) ? partial[tid - d] : 0;
        __syncthreads();
        partial[tid] += t;
        __syncthreads();
    }
    int offset = (tid > 0) ? partial[tid - 1] : 0;
    for (int i = 0; i < per; ++i)
        if (base + i < N_NODES) off[base + i] = offset + local[i];
    if (tid == 1023) off[N_NODES] = partial[1023];
}

__global__ void scatter_kernel(const int* __restrict__ edges, const int* __restrict__ flags,
                               const int* __restrict__ off, int* __restrict__ cursor,
                               int* __restrict__ csr_src) {
    int e = blockIdx.x * 256 + threadIdx.x;
    if (e >= N_E2) return;
    int i64 = flags[0];
    int src, dst;
    if (e < N_EDGES) {
        src = clampn(i64 ? edges[2 * e] : edges[e]);
        dst = clampn(i64 ? edges[2 * (N_EDGES + e)] : edges[N_EDGES + e]);
    } else { src = dst = e - N_EDGES; }
    int pos = off[dst] + atomicAdd(&cursor[dst], 1);
    csr_src[pos] = src;
}

// ---------------- encoder + step-0 projections (8 nodes/block, fp32) ----------------
__global__ __launch_bounds__(256) void enc_proj_kernel(
        const float* __restrict__ Xf,
        const float* __restrict__ encW, const float* __restrict__ encB,
        const float* __restrict__ Wl, const float* __restrict__ bl,
        const float* __restrict__ Wr, const float* __restrict__ br,
        __half* __restrict__ xlh, float* __restrict__ xr) {
    __shared__ float xs[8][DIM];
    __shared__ float h0[8][DIM];
    const int t = threadIdx.x, pp = t >> 6, d = t & 63;
    const int n0 = blockIdx.x * 8;
    ((float*)xs)[t]       = Xf[n0 * DIM + t];
    ((float*)xs)[t + 256] = Xf[n0 * DIM + t + 256];
    __syncthreads();
    float ah0 = encB[d], ah1 = encB[d];
    for (int k = 0; k < DIM; ++k) {
        float wv = encW[k * DIM + d];
        ah0 += xs[pp][k] * wv;
        ah1 += xs[pp + 4][k] * wv;
    }
    h0[pp][d]     = ah0;
    h0[pp + 4][d] = ah1;
    __syncthreads();
    float al[8] = {0,0,0,0,0,0,0,0}, ar[8] = {0,0,0,0,0,0,0,0};
    for (int k = 0; k < DIM; ++k) {
        float wl = Wl[k * HD + t], wr = Wr[k * HD + t];
        #pragma unroll
        for (int j = 0; j < 8; ++j) { al[j] += h0[j][k] * wl; ar[j] += h0[j][k] * wr; }
    }
    float bbl = bl[t], bbr = br[t];
    #pragma unroll
    for (int j = 0; j < 8; ++j) {
        xlh[(size_t)(n0 + j) * HD + t] = __float2half(al[j] + bbl);
        xr[(size_t)(n0 + j) * HD + t] = ar[j] + bbr;
    }
}

// ---------------- edge flash softmax-agg (block = node) -> gbuf (fp16) ----------------
// 4-deep register-ring gather pipeline: a wave's avg deg/4 ~ 4.3 edges, so the
// prologue issues essentially all row gathers before the first is consumed.
__global__ __launch_bounds__(256) void edge_agg_kernel(
        const __half* __restrict__ xlh, const float* __restrict__ xr,
        const float* __restrict__ att, const float* __restrict__ gbias,
        const int* __restrict__ off, const int* __restrict__ csr_src,
        __half* __restrict__ gbufh) {
    __shared__ float red_m[4][4];
    __shared__ float red_s[4][4];
    __shared__ float red_acc[4][HD];
    const int n = blockIdx.x;
    const int t = threadIdx.x, w = t >> 6, l = t & 63;
    const int e0 = off[n], e1 = off[n + 1];
    const float4 xr4 = ((const float4*)(xr + (size_t)n * HD))[l];
    const float4 at4 = ((const float4*)att)[l];

    float m = -1e30f, s = 0.f;
    float4 acc = {0.f, 0.f, 0.f, 0.f};
    const uint2 zero2 = {0u, 0u};
    int e = e0 + w;
    uint2 b0 = zero2, b1v = zero2, b2v = zero2, b3v = zero2;
    if (e < e1)      b0  = ((const uint2*)(xlh + (size_t)csr_src[e] * HD))[l];
    if (e + 4 < e1)  b1v = ((const uint2*)(xlh + (size_t)csr_src[e + 4] * HD))[l];
    if (e + 8 < e1)  b2v = ((const uint2*)(xlh + (size_t)csr_src[e + 8] * HD))[l];
    if (e + 12 < e1) b3v = ((const uint2*)(xlh + (size_t)csr_src[e + 12] * HD))[l];
    for (; e < e1; e += 4) {
        uint2 cur = b0;
        b0 = b1v; b1v = b2v; b2v = b3v;
        if (e + 16 < e1)
            b3v = ((const uint2*)(xlh + (size_t)csr_src[e + 16] * HD))[l];
        __half2 h01 = *reinterpret_cast<__half2*>(&cur.x);
        __half2 h23 = *reinterpret_cast<__half2*>(&cur.y);
        float2 f01 = __half22float2(h01);
        float2 f23 = __half22float2(h23);
        float c0 = f01.x, c1 = f01.y, c2 = f23.x, c3 = f23.y;
        float z0 = c0 + xr4.x, z1 = c1 + xr4.y, z2 = c2 + xr4.z, z3 = c3 + xr4.w;
        z0 = (z0 > 0.f) ? z0 : 0.2f * z0;
        z1 = (z1 > 0.f) ? z1 : 0.2f * z1;
        z2 = (z2 > 0.f) ? z2 : 0.2f * z2;
        z3 = (z3 > 0.f) ? z3 : 0.2f * z3;
        float p = z0 * at4.x + z1 * at4.y + z2 * at4.z + z3 * at4.w;
        #pragma unroll
        for (int mo = 8; mo; mo >>= 1) p += __shfl_xor(p, mo, 64);
        float nm = fmaxf(m, p);
        float sc = __expf(m - nm);
        float wv = __expf(p - nm);
        s = s * sc + wv;
        acc.x = acc.x * sc + wv * c0;
        acc.y = acc.y * sc + wv * c1;
        acc.z = acc.z * sc + wv * c2;
        acc.w = acc.w * sc + wv * c3;
        m = nm;
    }
    if ((l & 15) == 0) { red_m[w][l >> 4] = m; red_s[w][l >> 4] = s; }
    ((float4*)red_acc[w])[l] = acc;
    __syncthreads();
    {
        int hh = t >> 6;
        float m0 = red_m[0][hh], m1 = red_m[1][hh], m2 = red_m[2][hh], m3 = red_m[3][hh];
        float mm = fmaxf(fmaxf(m0, m1), fmaxf(m2, m3));
        float f0 = __expf(m0 - mm), f1 = __expf(m1 - mm),
              f2 = __expf(m2 - mm), f3 = __expf(m3 - mm);
        float ss = red_s[0][hh] * f0 + red_s[1][hh] * f1 +
                   red_s[2][hh] * f2 + red_s[3][hh] * f3;
        float aa = red_acc[0][t] * f0 + red_acc[1][t] * f1 +
                   red_acc[2][t] * f2 + red_acc[3][t] * f3;
        gbufh[(size_t)n * HD + t] = __float2half(aa / (ss + 1e-16f) + gbias[t]);
    }
}

// ---------------- MLP + ACT + next-step projections (4 nodes/block, dot2) --------
__global__ __launch_bounds__(256) void mlp_act_proj_kernel(
        const __half* __restrict__ gbufh, const __half* __restrict__ wp,
        const float* __restrict__ b1, const float* __restrict__ b2,
        const float* __restrict__ actW, const float* __restrict__ actB,
        const float* __restrict__ bl, const float* __restrict__ br,
        float* __restrict__ act_tot, float* __restrict__ final_,
        __half* __restrict__ xlh, float* __restrict__ xr, int do_proj) {
    __shared__ unsigned int gall_u[4][128];   // 4 nodes x 256 fp16 (half2-packed)
    __shared__ float part[4][HD];             // cross-wave reduce
    __shared__ __half us_h[4][DIM];
    __shared__ float hns[4][DIM];
    __shared__ __half hns_h[4][DIM];
    __shared__ float delta[4];
    const int t = threadIdx.x, pp = t >> 6, d = t & 63;
    const int n0 = blockIdx.x * 4;

    const unsigned int* Wlp = (const unsigned int*)wp;          // [32][256]
    const unsigned int* Wrp = Wlp + 8192;                       // [32][256]
    const unsigned int* W1p = Wlp + 16384;                      // [128][64]
    const unsigned int* W2p = Wlp + 24576;                      // [32][64]

    // stage 4 gbuf rows (2 KB)
    {
        const unsigned int* gb = (const unsigned int*)gbufh;
        ((unsigned int*)gall_u)[t]       = gb[(size_t)n0 * 128 + t];
        ((unsigned int*)gall_u)[t + 256] = gb[(size_t)n0 * 128 + t + 256];
    }
    __syncthreads();

    // MLP1: [256]->[64]; wave pp handles k2 in [pp*32, pp*32+32)
    {
        float acc[4] = {0.f, 0.f, 0.f, 0.f};
        for (int k2 = pp * 32; k2 < pp * 32 + 32; ++k2) {
            unsigned int w2 = W1p[k2 * 64 + d];
            #pragma unroll
            for (int j = 0; j < 4; ++j) acc[j] = dot2(gall_u[j][k2], w2, acc[j]);
        }
        #pragma unroll
        for (int j = 0; j < 4; ++j) part[j][t] = acc[j];
    }
    __syncthreads();
    {
        float v = part[pp][d] + part[pp][64 + d] + part[pp][128 + d] + part[pp][192 + d] + b1[d];
        us_h[pp][d] = __float2half(fmaxf(v, 0.f));
    }
    __syncthreads();

    // MLP2: [64]->[64]; wave pp handles k2 in [pp*8, pp*8+8)
    {
        const unsigned int* us_u = (const unsigned int*)us_h;  // [4][32]
        float acc[4] = {0.f, 0.f, 0.f, 0.f};
        for (int k2 = pp * 8; k2 < pp * 8 + 8; ++k2) {
            unsigned int w2 = W2p[k2 * 64 + d];
            #pragma unroll
            for (int j = 0; j < 4; ++j) acc[j] = dot2(us_u[j * 32 + k2], w2, acc[j]);
        }
        #pragma unroll
        for (int j = 0; j < 4; ++j) part[j][t] = acc[j];
    }
    __syncthreads();
    {
        float hv = part[pp][d] + part[pp][64 + d] + part[pp][128 + d] + part[pp][192 + d] + b2[d];
        hns[pp][d] = hv;
        hns_h[pp][d] = __float2half(hv);
    }
    __syncthreads();

    // ACT: wave pp -> node pp
    {
        float p = hns[pp][d] * actW[d];
        #pragma unroll
        for (int mo = 32; mo; mo >>= 1) p += __shfl_xor(p, mo, 64);
        if (d == 0) {
            float term = 1.f / (1.f + __expf(-(p + actB[0])));
            float tot = act_tot[n0 + pp];
            float nt = fminf(tot + term, 1.f);
            float dl = fminf(term, nt - tot);
            act_tot[n0 + pp] = tot + dl;
            delta[pp] = dl;
        }
    }
    __syncthreads();
    final_[(size_t)(n0 + pp) * DIM + d] += delta[pp] * hns[pp][d];

    // proj for next step: xl/xr = hn @ Wl/Wr + b
    if (do_proj) {
        const unsigned int* hn_u = (const unsigned int*)hns_h;  // [4][32]
        float al[4] = {0.f, 0.f, 0.f, 0.f}, ar[4] = {0.f, 0.f, 0.f, 0.f};
        for (int k2 = 0; k2 < 32; ++k2) {
            unsigned int wl2 = Wlp[k2 * 256 + t];
            unsigned int wr2 = Wrp[k2 * 256 + t];
            #pragma unroll
            for (int j = 0; j < 4; ++j) {
                unsigned int hh = hn_u[j * 32 + k2];
                al[j] = dot2(hh, wl2, al[j]);
                ar[j] = dot2(hh, wr2, ar[j]);
            }
        }
        float bbl = bl[t], bbr = br[t];
        #pragma unroll
        for (int j = 0; j < 4; ++j) {
            xlh[(size_t)(n0 + j) * HD + t] = __float2half(al[j] + bbl);
            xr[(size_t)(n0 + j) * HD + t] = ar[j] + bbr;
        }
    }
}

// ---------------- decoder + log_softmax ----------------
__global__ void decoder_kernel(const float* __restrict__ final_,
                               const float* __restrict__ decW, const float* __restrict__ decB,
                               const int* __restrict__ flags, void* __restrict__ outv) {
    int id = blockIdx.x * 256 + threadIdx.x;
    if (id >= N_NODES * N_PRED * N_CLASS) return;
    int n = id >> 5, r = id & 31, p = r >> 4, c = r & 15;
    float acc = decB[p * N_CLASS + c];
    for (int dd = 0; dd < DIM; ++dd)
        acc += final_[(size_t)n * DIM + dd] * decW[(p * DIM + dd) * N_CLASS + c];
    float mx = acc;
    #pragma unroll
    for (int mo = 8; mo; mo >>= 1) mx = fmaxf(mx, __shfl_xor(mx, mo, 64));
    float ex = __expf(acc - mx);
    float ss = ex;
    #pragma unroll
    for (int mo = 8; mo; mo >>= 1) ss += __shfl_xor(ss, mo, 64);
    float ov = acc - mx - logf(ss);
    int oi = p * (N_NODES * N_CLASS) + n * N_CLASS + c;
    if (flags[1]) ((bf16*)outv)[oi] = __float2bfloat16(ov);
    else          ((float*)outv)[oi] = ov;
}

// ---------------- host launcher ----------------
static size_t align256(size_t x) { return (x + 255) & ~size_t(255); }

extern "C" void kernel_launch(void* const* d_in, const int* in_sizes, int n_in,
                              void* d_out, int out_size, void* d_ws, size_t ws_size,
                              hipStream_t stream) {
    const int* edges = (const int*)d_in[1];

    static const int fids[17] = {0, 2, 3, 4, 5, 6, 7, 8, 9, 10, 11, 12, 13, 14, 15, 16, 17};
    ConvTable tab;
    int cum = 0;
    for (int i = 0; i < 17; ++i) {
        tab.src[i] = d_in[fids[i]];
        tab.start[i] = cum;
        cum += in_sizes[fids[i]];
    }
    tab.start[17] = cum;

    // workspace carve-up. Zero region contiguous: [deg cursor act_tot final_]
    char* w = (char*)d_ws;
    size_t o = 0;
    int* flags     = (int*)(w + o); o = align256(o + 16 * sizeof(int));
    int* off       = (int*)(w + o); o = align256(o + (N_NODES + 1) * sizeof(int));
    size_t zbase = o;
    int* deg       = (int*)(w + o); o = align256(o + N_NODES * sizeof(int));
    int* cursor    = (int*)(w + o); o = align256(o + N_NODES * sizeof(int));
    float* act_tot = (float*)(w + o); o = align256(o + N_NODES * sizeof(float));
    float* final_  = (float*)(w + o); o = align256(o + (size_t)N_NODES * DIM * sizeof(float));
    size_t zsize = o - zbase;
    int* csr_src   = (int*)(w + o); o = align256(o + N_E2 * sizeof(int));
    float* xf      = (float*)(w + o); o = align256(o + (size_t)cum * sizeof(float));
    __half* xlh    = (__half*)(w + o); o = align256(o + (size_t)N_NODES * HD * sizeof(__half));
    float* xr      = (float*)(w + o); o = align256(o + (size_t)N_NODES * HD * sizeof(float));
    __half* gbufh  = (__half*)(w + o); o = align256(o + (size_t)N_NODES * HD * sizeof(__half));
    __half* wpack  = (__half*)(w + o); o = align256(o + 53248 * sizeof(__half));
    if (o > ws_size) return;  // diagnostic: zero output => ws too small

    const float* Xf   = xf + tab.start[0];
    const float* encW = xf + tab.start[1];
    const float* encB = xf + tab.start[2];
    const float* Wl   = xf + tab.start[3];
    const float* bl   = xf + tab.start[4];
    const float* Wr   = xf + tab.start[5];
    const float* br   = xf + tab.start[6];
    const float* att  = xf + tab.start[7];
    const float* gbias= xf + tab.start[8];
    const float* b1   = xf + tab.start[10];
    const float* b2   = xf + tab.start[12];
    const float* actW = xf + tab.start[13];
    const float* actB = xf + tab.start[14];
    const float* decW = xf + tab.start[15];
    const float* decB = xf + tab.start[16];

    hipMemsetAsync(w + zbase, 0, zsize, stream);   // deg, cursor, act_tot, final_

    detect_kernel<<<1, 256, 0, stream>>>((const unsigned int*)d_in[1],
                                         (const unsigned short*)d_in[0], flags);
    convert_kernel<<<(cum + 255) / 256, 256, 0, stream>>>(tab, flags, xf);
    pack_kernel<<<(26624 + 255) / 256, 256, 0, stream>>>(
        xf, tab.start[3], tab.start[5], tab.start[9], tab.start[11], wpack);

    int eb = (N_E2 + 255) / 256;
    hist_kernel<<<eb, 256, 0, stream>>>(edges, flags, deg);
    scan_kernel<<<1, 1024, 0, stream>>>(deg, off);
    scatter_kernel<<<eb, 256, 0, stream>>>(edges, flags, off, cursor, csr_src);

    enc_proj_kernel<<<N_NODES / 8, 256, 0, stream>>>(Xf, encW, encB, Wl, bl, Wr, br, xlh, xr);

    for (int step = 0; step < N_STEPS; ++step) {
        edge_agg_kernel<<<N_NODES, 256, 0, stream>>>(xlh, xr, att, gbias, off, csr_src, gbufh);
        mlp_act_proj_kernel<<<N_NODES / 4, 256, 0, stream>>>(
            gbufh, wpack, b1, b2, actW, actB, bl, br,
            act_tot, final_, xlh, xr, (step < N_STEPS - 1) ? 1 : 0);
    }

    int db = (N_NODES * N_PRED * N_CLASS + 255) / 256;
    decoder_kernel<<<db, 256, 0, stream>>>(final_, decW, decB, flags, d_out);
}

// Round 9
// 324.388 us; speedup vs baseline: 5.4860x; 1.0448x over previous
//
#include <hip/hip_runtime.h>
#include <hip/hip_bf16.h>
#include <hip/hip_fp16.h>

#define N_NODES 10000
#define N_EDGES 160000
#define N_E2    (N_EDGES + N_NODES)   // with self-loops
#define DIM     64
#define HD      256                    // HEADS * DIM
#define N_PRED  2
#define N_CLASS 16
#define N_STEPS 4

typedef __hip_bfloat16 bf16;
__device__ __forceinline__ float b2f(bf16 v) { return __bfloat162float(v); }
__device__ __forceinline__ int clampn(int v) { return v < 0 ? 0 : (v >= N_NODES ? N_NODES - 1 : v); }

typedef _Float16 h2_t __attribute__((ext_vector_type(2)));

// fp16 pair dot with fp32 accumulate: 1 VALU op for 2 MACs (v_dot2_f32_f16)
__device__ __forceinline__ float dot2(unsigned int a, unsigned int b, float c) {
#if __has_builtin(__builtin_amdgcn_fdot2)
    h2_t av, bv;
    __builtin_memcpy(&av, &a, 4);
    __builtin_memcpy(&bv, &b, 4);
    return __builtin_amdgcn_fdot2(av, bv, c, false);
#else
    __half2 ah = *(__half2*)&a, bh = *(__half2*)&b;
    float2 af = __half22float2(ah), bf = __half22float2(bh);
    return c + af.x * bf.x + af.y * bf.y;
#endif
}

struct ConvTable {
    const void* src[17];
    int start[18];
};

// ---------------- dtype detection (1 block) ----------------
__global__ void detect_kernel(const unsigned int* __restrict__ e32,
                              const unsigned short* __restrict__ x16,
                              int* __restrict__ flags) {
    __shared__ int ce, cf;
    if (threadIdx.x == 0) { ce = 0; cf = 0; }
    __syncthreads();
    int le = 0;
    for (int i = threadIdx.x; i < 2048; i += 256)
        le += (e32[2 * i + 1] != 0u) ? 1 : 0;
    int lf = 0;
    for (int i = threadIdx.x; i < 1024; i += 256) {
        unsigned short u = x16[2 * i];
        int ex = (u >> 7) & 0xFF;
        lf += (u == 0 || (ex >= 114 && ex <= 141)) ? 1 : 0;
    }
    atomicAdd(&ce, le);
    atomicAdd(&cf, lf);
    __syncthreads();
    if (threadIdx.x == 0) {
        flags[0] = (ce < 1024) ? 1 : 0;   // edge_index is int64
        flags[1] = (cf >= 512) ? 1 : 0;   // floats are bf16
    }
}

// ---------------- normalize all float inputs to fp32 in workspace ----------------
__global__ void convert_kernel(ConvTable tab, const int* __restrict__ flags,
                               float* __restrict__ xf) {
    int i = blockIdx.x * 256 + threadIdx.x;
    if (i >= tab.start[17]) return;
    int j = 0;
    #pragma unroll
    for (int k = 1; k < 17; ++k) j += (i >= tab.start[k]) ? 1 : 0;
    int off = i - tab.start[j];
    float v;
    if (flags[1]) v = b2f(((const bf16*)tab.src[j])[off]);
    else          v = ((const float*)tab.src[j])[off];
    xf[i] = v;
}

// ---------------- pack Wl/Wr/W1/W2 into k-paired fp16 half2 layout ----------------
__global__ void pack_kernel(const float* __restrict__ xf,
                            int oWl, int oWr, int oW1, int oW2,
                            __half* __restrict__ wp) {
    int i = blockIdx.x * 256 + threadIdx.x;
    if (i >= 26624) return;
    int base, width, loc;
    if (i < 8192)       { loc = i;         base = oWl; width = 256; }
    else if (i < 16384) { loc = i - 8192;  base = oWr; width = 256; }
    else if (i < 24576) { loc = i - 16384; base = oW1; width = 64; }
    else                { loc = i - 24576; base = oW2; width = 64; }
    int k2 = loc / width, c = loc % width;
    wp[2 * i]     = __float2half(xf[base + (2 * k2) * width + c]);
    wp[2 * i + 1] = __float2half(xf[base + (2 * k2 + 1) * width + c]);
}

// ---------------- CSR by dst ----------------
__global__ void hist_kernel(const int* __restrict__ edges, const int* __restrict__ flags,
                            int* __restrict__ deg) {
    int e = blockIdx.x * 256 + threadIdx.x;
    if (e >= N_E2) return;
    int i64 = flags[0];
    int dst;
    if (e < N_EDGES) dst = clampn(i64 ? edges[2 * (N_EDGES + e)] : edges[N_EDGES + e]);
    else             dst = e - N_EDGES;
    atomicAdd(&deg[dst], 1);
}

__global__ void scan_kernel(const int* __restrict__ deg, int* __restrict__ off) {
    __shared__ int partial[1024];
    const int tid = threadIdx.x;
    const int per = (N_NODES + 1023) / 1024;  // 10
    int local[16];
    int base = tid * per;
    int s = 0;
    for (int i = 0; i < per; ++i) {
        int v = (base + i < N_NODES) ? deg[base + i] : 0;
        local[i] = s;
        s += v;
    }
    partial[tid] = s;
    __syncthreads();
    for (int d = 1; d < 1024; d <<= 1) {
        int t = (tid >= d) ? partial[tid - d] : 0;
        __syncthreads();
        partial[tid] += t;
        __syncthreads();
    }
    int offset = (tid > 0) ? partial[tid - 1] : 0;
    for (int i = 0; i < per; ++i)
        if (base + i < N_NODES) off[base + i] = offset + local[i];
    if (tid == 1023) off[N_NODES] = partial[1023];
}

__global__ void scatter_kernel(const int* __restrict__ edges, const int* __restrict__ flags,
                               const int* __restrict__ off, int* __restrict__ cursor,
                               int* __restrict__ csr_src) {
    int e = blockIdx.x * 256 + threadIdx.x;
    if (e >= N_E2) return;
    int i64 = flags[0];
    int src, dst;
    if (e < N_EDGES) {
        src = clampn(i64 ? edges[2 * e] : edges[e]);
        dst = clampn(i64 ? edges[2 * (N_EDGES + e)] : edges[N_EDGES + e]);
    } else { src = dst = e - N_EDGES; }
    int pos = off[dst] + atomicAdd(&cursor[dst], 1);
    csr_src[pos] = src;
}

// ---------------- encoder + step-0 projections (8 nodes/block, fp32) ----------------
__global__ __launch_bounds__(256) void enc_proj_kernel(
        const float* __restrict__ Xf,
        const float* __restrict__ encW, const float* __restrict__ encB,
        const float* __restrict__ Wl, const float* __restrict__ bl,
        const float* __restrict__ Wr, const float* __restrict__ br,
        __half* __restrict__ xlh, float* __restrict__ xr) {
    __shared__ float xs[8][DIM];
    __shared__ float h0[8][DIM];
    const int t = threadIdx.x, pp = t >> 6, d = t & 63;
    const int n0 = blockIdx.x * 8;
    ((float*)xs)[t]       = Xf[n0 * DIM + t];
    ((float*)xs)[t + 256] = Xf[n0 * DIM + t + 256];
    __syncthreads();
    float ah0 = encB[d], ah1 = encB[d];
    for (int k = 0; k < DIM; ++k) {
        float wv = encW[k * DIM + d];
        ah0 += xs[pp][k] * wv;
        ah1 += xs[pp + 4][k] * wv;
    }
    h0[pp][d]     = ah0;
    h0[pp + 4][d] = ah1;
    __syncthreads();
    float al[8] = {0,0,0,0,0,0,0,0}, ar[8] = {0,0,0,0,0,0,0,0};
    for (int k = 0; k < DIM; ++k) {
        float wl = Wl[k * HD + t], wr = Wr[k * HD + t];
        #pragma unroll
        for (int j = 0; j < 8; ++j) { al[j] += h0[j][k] * wl; ar[j] += h0[j][k] * wr; }
    }
    float bbl = bl[t], bbr = br[t];
    #pragma unroll
    for (int j = 0; j < 8; ++j) {
        xlh[(size_t)(n0 + j) * HD + t] = __float2half(al[j] + bbl);
        xr[(size_t)(n0 + j) * HD + t] = ar[j] + bbr;
    }
}

// ---------------- edge flash softmax-agg: ONE WAVE PER NODE ----------------
// No LDS, no barriers, no cross-wave merge. Wave walks all its node's edges
// with chunked (4+4) double-buffered row prefetch. Pad edges use a clamped
// address and p=-1e30 (contributes exp(-1e30-m)=0; self-loop guarantees a
// finite m after the first edge).
__global__ __launch_bounds__(256) void edge_agg_kernel(
        const __half* __restrict__ xlh, const float* __restrict__ xr,
        const float* __restrict__ att, const float* __restrict__ gbias,
        const int* __restrict__ off, const int* __restrict__ csr_src,
        __half* __restrict__ gbufh) {
    const int t = threadIdx.x, w = t >> 6, l = t & 63;
    const int n = blockIdx.x * 4 + w;                 // wave per node
    const int e0 = off[n], e1 = off[n + 1];           // deg >= 1 (self-loop)
    const int elast = e1 - 1;
    const float4 xr4 = ((const float4*)(xr + (size_t)n * HD))[l];
    const float4 at4 = ((const float4*)att)[l];

    float m = -1e30f, s = 0.f;
    float4 acc = {0.f, 0.f, 0.f, 0.f};
    uint2 A[4], B[4];
    #pragma unroll
    for (int i = 0; i < 4; ++i) {
        int ee = e0 + i; ee = (ee > elast) ? elast : ee;
        A[i] = ((const uint2*)(xlh + (size_t)csr_src[ee] * HD))[l];
    }
    for (int base = e0; base < e1; base += 4) {
        #pragma unroll
        for (int i = 0; i < 4; ++i) {
            int ee = base + 4 + i; ee = (ee > elast) ? elast : ee;
            B[i] = ((const uint2*)(xlh + (size_t)csr_src[ee] * HD))[l];
        }
        #pragma unroll
        for (int i = 0; i < 4; ++i) {
            const bool valid = (base + i) < e1;       // wave-uniform
            __half2 h01 = *reinterpret_cast<__half2*>(&A[i].x);
            __half2 h23 = *reinterpret_cast<__half2*>(&A[i].y);
            float2 f01 = __half22float2(h01);
            float2 f23 = __half22float2(h23);
            float c0 = f01.x, c1 = f01.y, c2 = f23.x, c3 = f23.y;
            float z0 = c0 + xr4.x, z1 = c1 + xr4.y, z2 = c2 + xr4.z, z3 = c3 + xr4.w;
            z0 = (z0 > 0.f) ? z0 : 0.2f * z0;
            z1 = (z1 > 0.f) ? z1 : 0.2f * z1;
            z2 = (z2 > 0.f) ? z2 : 0.2f * z2;
            z3 = (z3 > 0.f) ? z3 : 0.2f * z3;
            float p = z0 * at4.x + z1 * at4.y + z2 * at4.z + z3 * at4.w;
            #pragma unroll
            for (int mo = 8; mo; mo >>= 1) p += __shfl_xor(p, mo, 64);  // 16-lane head reduce
            p = valid ? p : -1e30f;
            float nm = fmaxf(m, p);
            float sc = __expf(m - nm);
            float wv = __expf(p - nm);
            s = s * sc + wv;
            acc.x = acc.x * sc + wv * c0;
            acc.y = acc.y * sc + wv * c1;
            acc.z = acc.z * sc + wv * c2;
            acc.w = acc.w * sc + wv * c3;
            m = nm;
        }
        #pragma unroll
        for (int i = 0; i < 4; ++i) A[i] = B[i];
    }
    const float inv = 1.f / (s + 1e-16f);
    const float4 gb4 = ((const float4*)gbias)[l];
    __half2 o01 = __floats2half2_rn(acc.x * inv + gb4.x, acc.y * inv + gb4.y);
    __half2 o23 = __floats2half2_rn(acc.z * inv + gb4.z, acc.w * inv + gb4.w);
    uint2 outv;
    outv.x = *(unsigned int*)&o01;
    outv.y = *(unsigned int*)&o23;
    ((uint2*)(gbufh + (size_t)n * HD))[l] = outv;
}

// ---------------- MLP + ACT + next-step projections (4 nodes/block, dot2) --------
__global__ __launch_bounds__(256) void mlp_act_proj_kernel(
        const __half* __restrict__ gbufh, const __half* __restrict__ wp,
        const float* __restrict__ b1, const float* __restrict__ b2,
        const float* __restrict__ actW, const float* __restrict__ actB,
        const float* __restrict__ bl, const float* __restrict__ br,
        float* __restrict__ act_tot, float* __restrict__ final_,
        __half* __restrict__ xlh, float* __restrict__ xr, int do_proj) {
    __shared__ unsigned int gall_u[4][128];   // 4 nodes x 256 fp16 (half2-packed)
    __shared__ float part[4][HD];             // cross-wave reduce
    __shared__ __half us_h[4][DIM];
    __shared__ float hns[4][DIM];
    __shared__ __half hns_h[4][DIM];
    __shared__ float delta[4];
    const int t = threadIdx.x, pp = t >> 6, d = t & 63;
    const int n0 = blockIdx.x * 4;

    const unsigned int* Wlp = (const unsigned int*)wp;          // [32][256]
    const unsigned int* Wrp = Wlp + 8192;                       // [32][256]
    const unsigned int* W1p = Wlp + 16384;                      // [128][64]
    const unsigned int* W2p = Wlp + 24576;                      // [32][64]

    {
        const unsigned int* gb = (const unsigned int*)gbufh;
        ((unsigned int*)gall_u)[t]       = gb[(size_t)n0 * 128 + t];
        ((unsigned int*)gall_u)[t + 256] = gb[(size_t)n0 * 128 + t + 256];
    }
    __syncthreads();

    // MLP1: [256]->[64]; wave pp handles k2 in [pp*32, pp*32+32)
    {
        float acc[4] = {0.f, 0.f, 0.f, 0.f};
        for (int k2 = pp * 32; k2 < pp * 32 + 32; ++k2) {
            unsigned int w2 = W1p[k2 * 64 + d];
            #pragma unroll
            for (int j = 0; j < 4; ++j) acc[j] = dot2(gall_u[j][k2], w2, acc[j]);
        }
        #pragma unroll
        for (int j = 0; j < 4; ++j) part[j][t] = acc[j];
    }
    __syncthreads();
    {
        float v = part[pp][d] + part[pp][64 + d] + part[pp][128 + d] + part[pp][192 + d] + b1[d];
        us_h[pp][d] = __float2half(fmaxf(v, 0.f));
    }
    __syncthreads();

    // MLP2: [64]->[64]; wave pp handles k2 in [pp*8, pp*8+8)
    {
        const unsigned int* us_u = (const unsigned int*)us_h;  // [4][32]
        float acc[4] = {0.f, 0.f, 0.f, 0.f};
        for (int k2 = pp * 8; k2 < pp * 8 + 8; ++k2) {
            unsigned int w2 = W2p[k2 * 64 + d];
            #pragma unroll
            for (int j = 0; j < 4; ++j) acc[j] = dot2(us_u[j * 32 + k2], w2, acc[j]);
        }
        #pragma unroll
        for (int j = 0; j < 4; ++j) part[j][t] = acc[j];
    }
    __syncthreads();
    {
        float hv = part[pp][d] + part[pp][64 + d] + part[pp][128 + d] + part[pp][192 + d] + b2[d];
        hns[pp][d] = hv;
        hns_h[pp][d] = __float2half(hv);
    }
    __syncthreads();

    // ACT: wave pp -> node pp
    {
        float p = hns[pp][d] * actW[d];
        #pragma unroll
        for (int mo = 32; mo; mo >>= 1) p += __shfl_xor(p, mo, 64);
        if (d == 0) {
            float term = 1.f / (1.f + __expf(-(p + actB[0])));
            float tot = act_tot[n0 + pp];
            float nt = fminf(tot + term, 1.f);
            float dl = fminf(term, nt - tot);
            act_tot[n0 + pp] = tot + dl;
            delta[pp] = dl;
        }
    }
    __syncthreads();
    final_[(size_t)(n0 + pp) * DIM + d] += delta[pp] * hns[pp][d];

    if (do_proj) {
        const unsigned int* hn_u = (const unsigned int*)hns_h;  // [4][32]
        float al[4] = {0.f, 0.f, 0.f, 0.f}, ar[4] = {0.f, 0.f, 0.f, 0.f};
        for (int k2 = 0; k2 < 32; ++k2) {
            unsigned int wl2 = Wlp[k2 * 256 + t];
            unsigned int wr2 = Wrp[k2 * 256 + t];
            #pragma unroll
            for (int j = 0; j < 4; ++j) {
                unsigned int hh = hn_u[j * 32 + k2];
                al[j] = dot2(hh, wl2, al[j]);
                ar[j] = dot2(hh, wr2, ar[j]);
            }
        }
        float bbl = bl[t], bbr = br[t];
        #pragma unroll
        for (int j = 0; j < 4; ++j) {
            xlh[(size_t)(n0 + j) * HD + t] = __float2half(al[j] + bbl);
            xr[(size_t)(n0 + j) * HD + t] = ar[j] + bbr;
        }
    }
}

// ---------------- decoder + log_softmax ----------------
__global__ void decoder_kernel(const float* __restrict__ final_,
                               const float* __restrict__ decW, const float* __restrict__ decB,
                               const int* __restrict__ flags, void* __restrict__ outv) {
    int id = blockIdx.x * 256 + threadIdx.x;
    if (id >= N_NODES * N_PRED * N_CLASS) return;
    int n = id >> 5, r = id & 31, p = r >> 4, c = r & 15;
    float acc = decB[p * N_CLASS + c];
    for (int dd = 0; dd < DIM; ++dd)
        acc += final_[(size_t)n * DIM + dd] * decW[(p * DIM + dd) * N_CLASS + c];
    float mx = acc;
    #pragma unroll
    for (int mo = 8; mo; mo >>= 1) mx = fmaxf(mx, __shfl_xor(mx, mo, 64));
    float ex = __expf(acc - mx);
    float ss = ex;
    #pragma unroll
    for (int mo = 8; mo; mo >>= 1) ss += __shfl_xor(ss, mo, 64);
    float ov = acc - mx - logf(ss);
    int oi = p * (N_NODES * N_CLASS) + n * N_CLASS + c;
    if (flags[1]) ((bf16*)outv)[oi] = __float2bfloat16(ov);
    else          ((float*)outv)[oi] = ov;
}

// ---------------- host launcher ----------------
static size_t align256(size_t x) { return (x + 255) & ~size_t(255); }

extern "C" void kernel_launch(void* const* d_in, const int* in_sizes, int n_in,
                              void* d_out, int out_size, void* d_ws, size_t ws_size,
                              hipStream_t stream) {
    const int* edges = (const int*)d_in[1];

    static const int fids[17] = {0, 2, 3, 4, 5, 6, 7, 8, 9, 10, 11, 12, 13, 14, 15, 16, 17};
    ConvTable tab;
    int cum = 0;
    for (int i = 0; i < 17; ++i) {
        tab.src[i] = d_in[fids[i]];
        tab.start[i] = cum;
        cum += in_sizes[fids[i]];
    }
    tab.start[17] = cum;

    // workspace carve-up. Zero region contiguous: [deg cursor act_tot final_]
    char* w = (char*)d_ws;
    size_t o = 0;
    int* flags     = (int*)(w + o); o = align256(o + 16 * sizeof(int));
    int* off       = (int*)(w + o); o = align256(o + (N_NODES + 1) * sizeof(int));
    size_t zbase = o;
    int* deg       = (int*)(w + o); o = align256(o + N_NODES * sizeof(int));
    int* cursor    = (int*)(w + o); o = align256(o + N_NODES * sizeof(int));
    float* act_tot = (float*)(w + o); o = align256(o + N_NODES * sizeof(float));
    float* final_  = (float*)(w + o); o = align256(o + (size_t)N_NODES * DIM * sizeof(float));
    size_t zsize = o - zbase;
    int* csr_src   = (int*)(w + o); o = align256(o + N_E2 * sizeof(int));
    float* xf      = (float*)(w + o); o = align256(o + (size_t)cum * sizeof(float));
    __half* xlh    = (__half*)(w + o); o = align256(o + (size_t)N_NODES * HD * sizeof(__half));
    float* xr      = (float*)(w + o); o = align256(o + (size_t)N_NODES * HD * sizeof(float));
    __half* gbufh  = (__half*)(w + o); o = align256(o + (size_t)N_NODES * HD * sizeof(__half));
    __half* wpack  = (__half*)(w + o); o = align256(o + 53248 * sizeof(__half));
    if (o > ws_size) return;  // diagnostic: zero output => ws too small

    const float* Xf   = xf + tab.start[0];
    const float* encW = xf + tab.start[1];
    const float* encB = xf + tab.start[2];
    const float* Wl   = xf + tab.start[3];
    const float* bl   = xf + tab.start[4];
    const float* Wr   = xf + tab.start[5];
    const float* br   = xf + tab.start[6];
    const float* att  = xf + tab.start[7];
    const float* gbias= xf + tab.start[8];
    const float* b1   = xf + tab.start[10];
    const float* b2   = xf + tab.start[12];
    const float* actW = xf + tab.start[13];
    const float* actB = xf + tab.start[14];
    const float* decW = xf + tab.start[15];
    const float* decB = xf + tab.start[16];

    hipMemsetAsync(w + zbase, 0, zsize, stream);   // deg, cursor, act_tot, final_

    detect_kernel<<<1, 256, 0, stream>>>((const unsigned int*)d_in[1],
                                         (const unsigned short*)d_in[0], flags);
    convert_kernel<<<(cum + 255) / 256, 256, 0, stream>>>(tab, flags, xf);
    pack_kernel<<<(26624 + 255) / 256, 256, 0, stream>>>(
        xf, tab.start[3], tab.start[5], tab.start[9], tab.start[11], wpack);

    int eb = (N_E2 + 255) / 256;
    hist_kernel<<<eb, 256, 0, stream>>>(edges, flags, deg);
    scan_kernel<<<1, 1024, 0, stream>>>(deg, off);
    scatter_kernel<<<eb, 256, 0, stream>>>(edges, flags, off, cursor, csr_src);

    enc_proj_kernel<<<N_NODES / 8, 256, 0, stream>>>(Xf, encW, encB, Wl, bl, Wr, br, xlh, xr);

    for (int step = 0; step < N_STEPS; ++step) {
        edge_agg_kernel<<<N_NODES / 4, 256, 0, stream>>>(xlh, xr, att, gbias, off, csr_src, gbufh);
        mlp_act_proj_kernel<<<N_NODES / 4, 256, 0, stream>>>(
            gbufh, wpack, b1, b2, actW, actB, bl, br,
            act_tot, final_, xlh, xr, (step < N_STEPS - 1) ? 1 : 0);
    }

    int db = (N_NODES * N_PRED * N_CLASS + 255) / 256;
    decoder_kernel<<<db, 256, 0, stream>>>(final_, decW, decB, flags, d_out);
}

// Round 11
// 298.574 us; speedup vs baseline: 5.9603x; 1.0865x over previous
//
#include <hip/hip_runtime.h>
#include <hip/hip_bf16.h>
#include <hip/hip_fp16.h>

#define N_NODES 10000
#define N_EDGES 160000
#define N_E2    (N_EDGES + N_NODES)   // with self-loops
#define DIM     64
#define HD      256                    // HEADS * DIM
#define N_PRED  2
#define N_CLASS 16
#define N_STEPS 4

typedef __hip_bfloat16 bf16;
__device__ __forceinline__ float b2f(bf16 v) { return __bfloat162float(v); }
__device__ __forceinline__ int clampn(int v) { return v < 0 ? 0 : (v >= N_NODES ? N_NODES - 1 : v); }

typedef _Float16 h2_t __attribute__((ext_vector_type(2)));

// fp16 pair dot with fp32 accumulate (v_dot2_f32_f16)
__device__ __forceinline__ float dot2(unsigned int a, unsigned int b, float c) {
#if __has_builtin(__builtin_amdgcn_fdot2)
    h2_t av, bv;
    __builtin_memcpy(&av, &a, 4);
    __builtin_memcpy(&bv, &b, 4);
    return __builtin_amdgcn_fdot2(av, bv, c, false);
#else
    __half2 ah = *(__half2*)&a, bh = *(__half2*)&b;
    float2 af = __half22float2(ah), bf = __half22float2(bh);
    return c + af.x * bf.x + af.y * bf.y;
#endif
}

struct ConvTable {
    const void* src[17];
    int start[18];
};

__device__ __forceinline__ float loadf(const void* p, int idx, int isbf16) {
    return isbf16 ? b2f(((const bf16*)p)[idx]) : ((const float*)p)[idx];
}

// ---------------- dispatch 1: dtype detection + zero deg/cursor ----------------
__global__ void detect_kernel(const unsigned int* __restrict__ e32,
                              const unsigned short* __restrict__ x16,
                              int* __restrict__ flags,
                              int* __restrict__ deg, int* __restrict__ cursor) {
    __shared__ int ce, cf;
    if (threadIdx.x == 0) { ce = 0; cf = 0; }
    __syncthreads();
    int le = 0;
    for (int i = threadIdx.x; i < 2048; i += 256)
        le += (e32[2 * i + 1] != 0u) ? 1 : 0;
    int lf = 0;
    for (int i = threadIdx.x; i < 1024; i += 256) {
        unsigned short u = x16[2 * i];
        int ex = (u >> 7) & 0xFF;
        lf += (u == 0 || (ex >= 114 && ex <= 141)) ? 1 : 0;
    }
    atomicAdd(&ce, le);
    atomicAdd(&cf, lf);
    for (int i = threadIdx.x; i < N_NODES; i += 256) { deg[i] = 0; cursor[i] = 0; }
    __syncthreads();
    if (threadIdx.x == 0) {
        flags[0] = (ce < 1024) ? 1 : 0;   // edge_index is int64
        flags[1] = (cf >= 512) ? 1 : 0;   // floats are bf16
    }
}

// ---------------- dispatch 2: convert || pack || hist (block-range split) --------
struct PreArgs {
    ConvTable tab;
    const void* Wl_raw; const void* Wr_raw; const void* W1_raw; const void* W2_raw;
    const int* edges;
    int cb, pb;          // block counts: convert, pack
};

__global__ void pre_kernel(PreArgs a, const int* __restrict__ flags,
                           float* __restrict__ xf, __half* __restrict__ wp,
                           int* __restrict__ deg) {
    const int b = blockIdx.x, t = threadIdx.x;
    const int isb = flags[1];
    if (b < a.cb) {
        int i = b * 256 + t;
        if (i >= a.tab.start[17]) return;
        int j = 0;
        #pragma unroll
        for (int k = 1; k < 17; ++k) j += (i >= a.tab.start[k]) ? 1 : 0;
        xf[i] = loadf(a.tab.src[j], i - a.tab.start[j], isb);
    } else if (b < a.cb + a.pb) {
        int i = (b - a.cb) * 256 + t;
        if (i >= 26624) return;
        const void* base; int width, loc;
        if (i < 8192)       { loc = i;         base = a.Wl_raw; width = 256; }
        else if (i < 16384) { loc = i - 8192;  base = a.Wr_raw; width = 256; }
        else if (i < 24576) { loc = i - 16384; base = a.W1_raw; width = 64; }
        else                { loc = i - 24576; base = a.W2_raw; width = 64; }
        int k2 = loc / width, c = loc % width;
        wp[2 * i]     = __float2half(loadf(base, (2 * k2) * width + c, isb));
        wp[2 * i + 1] = __float2half(loadf(base, (2 * k2 + 1) * width + c, isb));
    } else {
        int e = (b - a.cb - a.pb) * 256 + t;
        if (e >= N_E2) return;
        int i64 = flags[0];
        int dst;
        if (e < N_EDGES) dst = clampn(i64 ? a.edges[2 * (N_EDGES + e)] : a.edges[N_EDGES + e]);
        else             dst = e - N_EDGES;
        atomicAdd(&deg[dst], 1);
    }
}

// ---------------- dispatch 3: exclusive scan ----------------
__global__ void scan_kernel(const int* __restrict__ deg, int* __restrict__ off) {
    __shared__ int partial[1024];
    const int tid = threadIdx.x;
    const int per = (N_NODES + 1023) / 1024;  // 10
    int local[16];
    int base = tid * per;
    int s = 0;
    for (int i = 0; i < per; ++i) {
        int v = (base + i < N_NODES) ? deg[base + i] : 0;
        local[i] = s;
        s += v;
    }
    partial[tid] = s;
    __syncthreads();
    for (int d = 1; d < 1024; d <<= 1) {
        int t = (tid >= d) ? partial[tid - d] : 0;
        __syncthreads();
        partial[tid] += t;
        __syncthreads();
    }
    int offset = (tid > 0) ? partial[tid - 1] : 0;
    for (int i = 0; i < per; ++i)
        if (base + i < N_NODES) off[base + i] = offset + local[i];
    if (tid == 1023) off[N_NODES] = partial[1023];
}

// ---------------- dispatch 4: scatter || (encoder + proj0 + zero act/final) ------
struct SEArgs {
    const int* edges;
    const int* off;
    int* cursor;
    int* csr_src;
    const float* xf;
    int sX, sEncW, sEncB, sWl, sBl, sWr, sBr;
    __half* xlh;
    float* xr;
    float* act_tot;
    float* final_;
    int sb;              // scatter block count
};

__global__ __launch_bounds__(256) void scatter_enc_kernel(SEArgs a, const int* __restrict__ flags) {
    const int b = blockIdx.x, t = threadIdx.x;
    if (b < a.sb) {
        int e = b * 256 + t;
        if (e >= N_E2) return;
        int i64 = flags[0];
        int src, dst;
        if (e < N_EDGES) {
            src = clampn(i64 ? a.edges[2 * e] : a.edges[e]);
            dst = clampn(i64 ? a.edges[2 * (N_EDGES + e)] : a.edges[N_EDGES + e]);
        } else { src = dst = e - N_EDGES; }
        int pos = a.off[dst] + atomicAdd(&a.cursor[dst], 1);
        a.csr_src[pos] = src;
        return;
    }
    // encoder + step-0 projections, 8 nodes/block
    __shared__ float xs[8][DIM];
    __shared__ float h0[8][DIM];
    const int pp = t >> 6, d = t & 63;
    const int n0 = (b - a.sb) * 8;
    const float* Xf   = a.xf + a.sX;
    const float* encW = a.xf + a.sEncW;
    const float* encB = a.xf + a.sEncB;
    const float* Wl   = a.xf + a.sWl;
    const float* bl   = a.xf + a.sBl;
    const float* Wr   = a.xf + a.sWr;
    const float* br   = a.xf + a.sBr;
    ((float*)xs)[t]       = Xf[n0 * DIM + t];
    ((float*)xs)[t + 256] = Xf[n0 * DIM + t + 256];
    a.final_[(size_t)n0 * DIM + t]       = 0.f;
    a.final_[(size_t)n0 * DIM + t + 256] = 0.f;
    if (t < 8) a.act_tot[n0 + t] = 0.f;
    __syncthreads();
    float ah0 = encB[d], ah1 = encB[d];
    for (int k = 0; k < DIM; ++k) {
        float wv = encW[k * DIM + d];
        ah0 += xs[pp][k] * wv;
        ah1 += xs[pp + 4][k] * wv;
    }
    h0[pp][d]     = ah0;
    h0[pp + 4][d] = ah1;
    __syncthreads();
    float al[8] = {0,0,0,0,0,0,0,0}, ar[8] = {0,0,0,0,0,0,0,0};
    for (int k = 0; k < DIM; ++k) {
        float wl = Wl[k * HD + t], wr = Wr[k * HD + t];
        #pragma unroll
        for (int j = 0; j < 8; ++j) { al[j] += h0[j][k] * wl; ar[j] += h0[j][k] * wr; }
    }
    float bbl = bl[t], bbr = br[t];
    #pragma unroll
    for (int j = 0; j < 8; ++j) {
        a.xlh[(size_t)(n0 + j) * HD + t] = __float2half(al[j] + bbl);
        a.xr[(size_t)(n0 + j) * HD + t] = ar[j] + bbr;
    }
}

// ---------------- dispatches 5-8: fused step kernel (DOUBLE-BUFFERED xl/xr) ------
// Phase 1: wave w = node n0+w full online-softmax edge walk reading xlh_in/xr_in,
// result -> LDS. Phase 2: MLP + ACT + proj writing xlh_out/xr_out (separate
// buffers: other blocks may still be reading xlh_in in phase 1 — the round-10
// in-place write was a cross-block RAW race).
__global__ __launch_bounds__(256) void step_kernel(
        const __half* __restrict__ xlh_in, const float* __restrict__ xr_in,
        const float* __restrict__ att, const float* __restrict__ gbias,
        const int* __restrict__ off, const int* __restrict__ csr_src,
        const __half* __restrict__ wp,
        const float* __restrict__ b1, const float* __restrict__ b2,
        const float* __restrict__ actW, const float* __restrict__ actB,
        const float* __restrict__ bl, const float* __restrict__ br,
        float* __restrict__ act_tot, float* __restrict__ final_,
        __half* __restrict__ xlh_out, float* __restrict__ xr_out, int do_proj) {
    __shared__ __align__(16) unsigned int gall_u[4][128];  // 4 nodes x 256 fp16
    __shared__ float part[4][HD];
    __shared__ __half us_h[4][DIM];
    __shared__ float hns[4][DIM];
    __shared__ __half hns_h[4][DIM];
    __shared__ float delta[4];
    const int t = threadIdx.x, w = t >> 6, l = t & 63;
    const int pp = w, d = l;
    const int n0 = blockIdx.x * 4;
    const int n = n0 + w;

    // ---- Phase 1: edge flash softmax-agg (wave per node) ----
    {
        const int e0 = off[n], e1 = off[n + 1];
        const int elast = e1 - 1;
        const float4 xr4 = ((const float4*)(xr_in + (size_t)n * HD))[l];
        const float4 at4 = ((const float4*)att)[l];
        float m = -1e30f, s = 0.f;
        float4 acc = {0.f, 0.f, 0.f, 0.f};
        uint2 A[4], B[4];
        #pragma unroll
        for (int i = 0; i < 4; ++i) {
            int ee = e0 + i; ee = (ee > elast) ? elast : ee;
            A[i] = ((const uint2*)(xlh_in + (size_t)csr_src[ee] * HD))[l];
        }
        for (int base = e0; base < e1; base += 4) {
            #pragma unroll
            for (int i = 0; i < 4; ++i) {
                int ee = base + 4 + i; ee = (ee > elast) ? elast : ee;
                B[i] = ((const uint2*)(xlh_in + (size_t)csr_src[ee] * HD))[l];
            }
            #pragma unroll
            for (int i = 0; i < 4; ++i) {
                const bool valid = (base + i) < e1;   // wave-uniform
                __half2 h01 = *reinterpret_cast<__half2*>(&A[i].x);
                __half2 h23 = *reinterpret_cast<__half2*>(&A[i].y);
                float2 f01 = __half22float2(h01);
                float2 f23 = __half22float2(h23);
                float c0 = f01.x, c1 = f01.y, c2 = f23.x, c3 = f23.y;
                float z0 = c0 + xr4.x, z1 = c1 + xr4.y, z2 = c2 + xr4.z, z3 = c3 + xr4.w;
                z0 = (z0 > 0.f) ? z0 : 0.2f * z0;
                z1 = (z1 > 0.f) ? z1 : 0.2f * z1;
                z2 = (z2 > 0.f) ? z2 : 0.2f * z2;
                z3 = (z3 > 0.f) ? z3 : 0.2f * z3;
                float p = z0 * at4.x + z1 * at4.y + z2 * at4.z + z3 * at4.w;
                #pragma unroll
                for (int mo = 8; mo; mo >>= 1) p += __shfl_xor(p, mo, 64);
                p = valid ? p : -1e30f;
                float nm = fmaxf(m, p);
                float sc = __expf(m - nm);
                float wv = __expf(p - nm);
                s = s * sc + wv;
                acc.x = acc.x * sc + wv * c0;
                acc.y = acc.y * sc + wv * c1;
                acc.z = acc.z * sc + wv * c2;
                acc.w = acc.w * sc + wv * c3;
                m = nm;
            }
            #pragma unroll
            for (int i = 0; i < 4; ++i) A[i] = B[i];
        }
        const float inv = 1.f / (s + 1e-16f);
        const float4 gb4 = ((const float4*)gbias)[l];
        __half2 o01 = __floats2half2_rn(acc.x * inv + gb4.x, acc.y * inv + gb4.y);
        __half2 o23 = __floats2half2_rn(acc.z * inv + gb4.z, acc.w * inv + gb4.w);
        uint2 outv;
        outv.x = *(unsigned int*)&o01;
        outv.y = *(unsigned int*)&o23;
        ((uint2*)gall_u[w])[l] = outv;     // g stays in LDS
    }
    __syncthreads();

    // ---- Phase 2: MLP + ACT + proj (4 nodes, dot2) ----
    const unsigned int* Wlp = (const unsigned int*)wp;          // [32][256]
    const unsigned int* Wrp = Wlp + 8192;                       // [32][256]
    const unsigned int* W1p = Wlp + 16384;                      // [128][64]
    const unsigned int* W2p = Wlp + 24576;                      // [32][64]

    {
        float acc[4] = {0.f, 0.f, 0.f, 0.f};
        for (int k2 = pp * 32; k2 < pp * 32 + 32; ++k2) {
            unsigned int w2 = W1p[k2 * 64 + d];
            #pragma unroll
            for (int j = 0; j < 4; ++j) acc[j] = dot2(gall_u[j][k2], w2, acc[j]);
        }
        #pragma unroll
        for (int j = 0; j < 4; ++j) part[j][t] = acc[j];
    }
    __syncthreads();
    {
        float v = part[pp][d] + part[pp][64 + d] + part[pp][128 + d] + part[pp][192 + d] + b1[d];
        us_h[pp][d] = __float2half(fmaxf(v, 0.f));
    }
    __syncthreads();
    {
        const unsigned int* us_u = (const unsigned int*)us_h;  // [4][32]
        float acc[4] = {0.f, 0.f, 0.f, 0.f};
        for (int k2 = pp * 8; k2 < pp * 8 + 8; ++k2) {
            unsigned int w2 = W2p[k2 * 64 + d];
            #pragma unroll
            for (int j = 0; j < 4; ++j) acc[j] = dot2(us_u[j * 32 + k2], w2, acc[j]);
        }
        #pragma unroll
        for (int j = 0; j < 4; ++j) part[j][t] = acc[j];
    }
    __syncthreads();
    {
        float hv = part[pp][d] + part[pp][64 + d] + part[pp][128 + d] + part[pp][192 + d] + b2[d];
        hns[pp][d] = hv;
        hns_h[pp][d] = __float2half(hv);
    }
    __syncthreads();
    {
        float p = hns[pp][d] * actW[d];
        #pragma unroll
        for (int mo = 32; mo; mo >>= 1) p += __shfl_xor(p, mo, 64);
        if (d == 0) {
            float term = 1.f / (1.f + __expf(-(p + actB[0])));
            float tot = act_tot[n0 + pp];
            float nt = fminf(tot + term, 1.f);
            float dl = fminf(term, nt - tot);
            act_tot[n0 + pp] = tot + dl;
            delta[pp] = dl;
        }
    }
    __syncthreads();
    final_[(size_t)(n0 + pp) * DIM + d] += delta[pp] * hns[pp][d];

    if (do_proj) {
        const unsigned int* hn_u = (const unsigned int*)hns_h;  // [4][32]
        float al[4] = {0.f, 0.f, 0.f, 0.f}, ar[4] = {0.f, 0.f, 0.f, 0.f};
        for (int k2 = 0; k2 < 32; ++k2) {
            unsigned int wl2 = Wlp[k2 * 256 + t];
            unsigned int wr2 = Wrp[k2 * 256 + t];
            #pragma unroll
            for (int j = 0; j < 4; ++j) {
                unsigned int hh = hn_u[j * 32 + k2];
                al[j] = dot2(hh, wl2, al[j]);
                ar[j] = dot2(hh, wr2, ar[j]);
            }
        }
        float bbl = bl[t], bbr = br[t];
        #pragma unroll
        for (int j = 0; j < 4; ++j) {
            xlh_out[(size_t)(n0 + j) * HD + t] = __float2half(al[j] + bbl);
            xr_out[(size_t)(n0 + j) * HD + t] = ar[j] + bbr;
        }
    }
}

// ---------------- dispatch 9: decoder + log_softmax ----------------
__global__ void decoder_kernel(const float* __restrict__ final_,
                               const float* __restrict__ decW, const float* __restrict__ decB,
                               const int* __restrict__ flags, void* __restrict__ outv) {
    int id = blockIdx.x * 256 + threadIdx.x;
    if (id >= N_NODES * N_PRED * N_CLASS) return;
    int n = id >> 5, r = id & 31, p = r >> 4, c = r & 15;
    float acc = decB[p * N_CLASS + c];
    for (int dd = 0; dd < DIM; ++dd)
        acc += final_[(size_t)n * DIM + dd] * decW[(p * DIM + dd) * N_CLASS + c];
    float mx = acc;
    #pragma unroll
    for (int mo = 8; mo; mo >>= 1) mx = fmaxf(mx, __shfl_xor(mx, mo, 64));
    float ex = __expf(acc - mx);
    float ss = ex;
    #pragma unroll
    for (int mo = 8; mo; mo >>= 1) ss += __shfl_xor(ss, mo, 64);
    float ov = acc - mx - logf(ss);
    int oi = p * (N_NODES * N_CLASS) + n * N_CLASS + c;
    if (flags[1]) ((bf16*)outv)[oi] = __float2bfloat16(ov);
    else          ((float*)outv)[oi] = ov;
}

// ---------------- host launcher ----------------
static size_t align256(size_t x) { return (x + 255) & ~size_t(255); }

extern "C" void kernel_launch(void* const* d_in, const int* in_sizes, int n_in,
                              void* d_out, int out_size, void* d_ws, size_t ws_size,
                              hipStream_t stream) {
    const int* edges = (const int*)d_in[1];

    static const int fids[17] = {0, 2, 3, 4, 5, 6, 7, 8, 9, 10, 11, 12, 13, 14, 15, 16, 17};
    ConvTable tab;
    int cum = 0;
    for (int i = 0; i < 17; ++i) {
        tab.src[i] = d_in[fids[i]];
        tab.start[i] = cum;
        cum += in_sizes[fids[i]];
    }
    tab.start[17] = cum;

    // workspace carve-up (~37 MB; harness poisons ~268 MB of ws, so capacity is fine)
    char* w = (char*)d_ws;
    size_t o = 0;
    int* flags     = (int*)(w + o); o = align256(o + 16 * sizeof(int));
    int* off       = (int*)(w + o); o = align256(o + (N_NODES + 1) * sizeof(int));
    int* deg       = (int*)(w + o); o = align256(o + N_NODES * sizeof(int));
    int* cursor    = (int*)(w + o); o = align256(o + N_NODES * sizeof(int));
    float* act_tot = (float*)(w + o); o = align256(o + N_NODES * sizeof(float));
    float* final_  = (float*)(w + o); o = align256(o + (size_t)N_NODES * DIM * sizeof(float));
    int* csr_src   = (int*)(w + o); o = align256(o + N_E2 * sizeof(int));
    float* xf      = (float*)(w + o); o = align256(o + (size_t)cum * sizeof(float));
    __half* xlh_a  = (__half*)(w + o); o = align256(o + (size_t)N_NODES * HD * sizeof(__half));
    float* xr_a    = (float*)(w + o); o = align256(o + (size_t)N_NODES * HD * sizeof(float));
    __half* xlh_b  = (__half*)(w + o); o = align256(o + (size_t)N_NODES * HD * sizeof(__half));
    float* xr_b    = (float*)(w + o); o = align256(o + (size_t)N_NODES * HD * sizeof(float));
    __half* wpack  = (__half*)(w + o); o = align256(o + 53248 * sizeof(__half));
    if (o > ws_size) return;  // diagnostic: zero output => ws too small

    const float* att  = xf + tab.start[7];
    const float* gbias= xf + tab.start[8];
    const float* b1   = xf + tab.start[10];
    const float* b2   = xf + tab.start[12];
    const float* actW = xf + tab.start[13];
    const float* actB = xf + tab.start[14];
    const float* decW = xf + tab.start[15];
    const float* decB = xf + tab.start[16];

    // 1: detect + zero deg/cursor
    detect_kernel<<<1, 256, 0, stream>>>((const unsigned int*)d_in[1],
                                         (const unsigned short*)d_in[0], flags, deg, cursor);

    // 2: convert || pack || hist
    PreArgs pa;
    pa.tab = tab;
    pa.Wl_raw = d_in[4]; pa.Wr_raw = d_in[6]; pa.W1_raw = d_in[10]; pa.W2_raw = d_in[12];
    pa.edges = edges;
    pa.cb = (cum + 255) / 256;
    pa.pb = (26624 + 255) / 256;
    int hb = (N_E2 + 255) / 256;
    pre_kernel<<<pa.cb + pa.pb + hb, 256, 0, stream>>>(pa, flags, xf, wpack, deg);

    // 3: scan
    scan_kernel<<<1, 1024, 0, stream>>>(deg, off);

    // 4: scatter || enc+proj0 (+zero act/final)
    SEArgs se;
    se.edges = edges; se.off = off; se.cursor = cursor; se.csr_src = csr_src;
    se.xf = xf;
    se.sX = tab.start[0]; se.sEncW = tab.start[1]; se.sEncB = tab.start[2];
    se.sWl = tab.start[3]; se.sBl = tab.start[4]; se.sWr = tab.start[5]; se.sBr = tab.start[6];
    se.xlh = xlh_a; se.xr = xr_a; se.act_tot = act_tot; se.final_ = final_;
    se.sb = hb;
    scatter_enc_kernel<<<hb + N_NODES / 8, 256, 0, stream>>>(se, flags);

    // 5-8: fused universal-transformer steps, ping-pong xl/xr buffers
    __half* xl_in = xlh_a;  float* xr_in = xr_a;
    __half* xl_out = xlh_b; float* xr_out = xr_b;
    for (int step = 0; step < N_STEPS; ++step) {
        step_kernel<<<N_NODES / 4, 256, 0, stream>>>(
            xl_in, xr_in, att, gbias, off, csr_src, wpack,
            b1, b2, actW, actB,
            xf + tab.start[4], xf + tab.start[6],
            act_tot, final_, xl_out, xr_out, (step < N_STEPS - 1) ? 1 : 0);
        __half* th = xl_in; xl_in = xl_out; xl_out = th;
        float* tf = xr_in; xr_in = xr_out; xr_out = tf;
    }

    // 9: decoder
    int db = (N_NODES * N_PRED * N_CLASS + 255) / 256;
    decoder_kernel<<<db, 256, 0, stream>>>(final_, decW, decB, flags, d_out);
}